// Round 5
// baseline (1037.380 us; speedup 1.0000x reference)
//
#include <hip/hip_runtime.h>
#include <cmath>
#include <complex>
#include <cstdio>
#include <cstring>
#include <algorithm>

#define E_EDGES 32768
#define NNODES  2048

// ============================ host-side CG tables ============================
namespace cgt {

static double fct(int n){
  static const double f[13] = {1.,1.,2.,6.,24.,120.,720.,5040.,40320.,362880.,
                               3628800.,39916800.,479001600.};
  return f[n];
}

static double cg(int j1,int m1,int j2,int m2,int j3,int m3){
  if (m1+m2 != m3) return 0.0;
  double pre = std::sqrt((2*j3+1)*fct(j1+j2-j3)*fct(j1-j2+j3)*fct(-j1+j2+j3)/fct(j1+j2+j3+1));
  pre *= std::sqrt(fct(j3+m3)*fct(j3-m3)*fct(j1-m1)*fct(j1+m1)*fct(j2-m2)*fct(j2+m2));
  int kmin = 0;
  if (j2-j3-m1 > kmin) kmin = j2-j3-m1;
  if (j1-j3+m2 > kmin) kmin = j1-j3+m2;
  int kmax = j1+j2-j3;
  if (j1-m1 < kmax) kmax = j1-m1;
  if (j2+m2 < kmax) kmax = j2+m2;
  double s = 0.0;
  for (int k=kmin;k<=kmax;k++){
    double d = fct(k)*fct(j1+j2-j3-k)*fct(j1-m1-k)*fct(j2+m2-k)*fct(j3-j2+m1+k)*fct(j3-j1-m2+k);
    s += ((k&1)? -1.0:1.0)/d;
  }
  return pre*s;
}

typedef std::complex<double> cd;

static void umat(int l, cd U[7][7]){
  for (int a=0;a<7;a++) for (int b=0;b<7;b++) U[a][b]=cd(0,0);
  U[l][l] = cd(1,0);
  double s2 = 1.0/std::sqrt(2.0);
  for (int m=1;m<=l;m++){
    double sg = (m&1)? -1.0 : 1.0;
    U[l+m][l-m] = cd(s2,0);
    U[l+m][l+m] = cd(sg*s2,0);
    U[l-m][l-m] = cd(0, s2);
    U[l-m][l+m] = cd(0, -sg*s2);
  }
}

static bool realCoupling(int l1,int l2,int l3, double T[7][7][7]){
  cd U1[7][7],U2[7][7],U3[7][7];
  umat(l1,U1); umat(l2,U2); umat(l3,U3);
  int n1=2*l1+1, n2=2*l2+1, n3=2*l3+1;
  double Cg[7][7][7];
  for (int m=0;m<n1;m++) for(int n=0;n<n2;n++) for(int k=0;k<n3;k++)
    Cg[m][n][k] = cg(l1,m-l1,l2,n-l2,l3,k-l3);
  double Tr[7][7][7], Ti[7][7][7];
  double nr=0, ni=0;
  for (int a=0;a<n1;a++) for(int b=0;b<n2;b++) for(int c=0;c<n3;c++){
    cd s(0,0);
    for (int m=0;m<n1;m++){
      if (U1[a][m]==cd(0,0)) continue;
      for (int n=0;n<n2;n++){
        if (U2[b][n]==cd(0,0)) continue;
        for (int k=0;k<n3;k++){
          double cgv = Cg[m][n][k];
          if (cgv==0.0) continue;
          s += U1[a][m]*U2[b][n]*std::conj(U3[c][k])*cgv;
        }
      }
    }
    Tr[a][b][c]=s.real(); Ti[a][b][c]=s.imag();
    nr += s.real()*s.real(); ni += s.imag()*s.imag();
  }
  bool useR = (nr >= ni);
  double nn = std::sqrt(useR? nr : ni);
  if (nn < 1e-8) return false;
  for (int a=0;a<n1;a++)for(int b=0;b<n2;b++)for(int c=0;c<n3;c++)
    T[a][b][c] = (useR? Tr[a][b][c] : Ti[a][b][c])/nn;
  return true;
}

struct Tables {
  float val[4096];
  int   ij[4096];        // (a_abs) | (b_abs<<8), entries grouped by (path, c)
  int   pmeta[40*4];     // per SLOT: tpOff(orig layout), entStart, entCount, kdim
  int   ccnt[40*8];      // per SLOT: entry count for each c (kd <= 7)
  int   l3base[4];
  int   l3np[4];
  int   npaths;
  int   nent;
  int   tptot;
  // --- pair/TD tables for the fused Vn GEMM (l>=1 slots only) ---
  int   pairs[256];      // (a_abs*17) | (b_abs*17 << 8): direct padded-LDS idx
  float TD[256*30*8];    // TD[pair][slot-4][kloc] = T*sqrt(2l3+1)
  int   sl_origc[40];    // per slot: original c-base (origIdxInL*16) for Wv rows
  int   npairs;          // padded even
};

struct PathTmp {
  int l1,l2,l3, tpoff, kd;
  int ec;                 // total nonzero entries
  double T[7][7][7];
};

static void build(Tables& tb){
  static PathTmp paths[40];
  int np = 0, tpoff = 0;
  int l3start[5];
  for (int l3=0;l3<=3;l3++){
    tb.l3base[l3] = tpoff;
    l3start[l3] = np;
    int kd = 2*l3+1;
    for (int l1=0;l1<=3;l1++) for (int l2=0;l2<=3;l2++){
      int lo = (l1>l2)? l1-l2 : l2-l1;
      int hi = std::min(l1+l2,3);
      if (l3 < lo || l3 > hi) continue;
      PathTmp& pt = paths[np];
      if (!realCoupling(l1,l2,l3,pt.T)) continue;
      pt.l1=l1; pt.l2=l2; pt.l3=l3; pt.kd=kd; pt.tpoff=tpoff;
      double scale = std::sqrt((double)kd);
      int cnt = 0;
      for (int a=0;a<2*l1+1;a++)for(int b=0;b<2*l2+1;b++)for(int c=0;c<kd;c++)
        if (std::fabs(pt.T[a][b][c]*scale) > 1e-7) cnt++;
      pt.ec = cnt;
      tpoff += 16*kd;
      np++;
    }
  }
  l3start[4] = np;
  for (int l3=0;l3<=3;l3++) tb.l3np[l3] = l3start[l3+1]-l3start[l3];
  static int order[40];
  for (int i=0;i<np;i++) order[i]=i;
  for (int l3=0;l3<=3;l3++)
    std::sort(order+l3start[l3], order+l3start[l3+1],
              [&](int a,int b){ return paths[a].ec > paths[b].ec; });
  // emit entries grouped by (slot, c); build pair map + TD for l>=1 slots
  std::memset(tb.TD, 0, sizeof(tb.TD));
  static int pmap[16][16];
  for (int i=0;i<16;i++) for (int j=0;j<16;j++) pmap[i][j] = -1;
  int npr = 0;
  int ep = 0;
  for (int slot=0; slot<np; slot++){
    const PathTmp& pt = paths[order[slot]];
    double scale = std::sqrt((double)pt.kd);
    int s1 = pt.l1*pt.l1, s2 = pt.l2*pt.l2;
    tb.pmeta[slot*4+0] = pt.tpoff;
    tb.pmeta[slot*4+1] = ep;
    tb.sl_origc[slot] = ((pt.tpoff - tb.l3base[pt.l3]) / (16*pt.kd)) * 16;
    int tot = 0;
    for (int c=0;c<pt.kd;c++){
      int cnt = 0;
      for (int a=0;a<2*pt.l1+1;a++)for(int b=0;b<2*pt.l2+1;b++){
        double v = pt.T[a][b][c]*scale;
        if (std::fabs(v) > 1e-7){
          tb.val[ep] = (float)v;
          tb.ij[ep]  = (s1+a) | ((s2+b)<<8);
          ep++; cnt++;
          if (pt.l3 >= 1){
            int aa = s1+a, bb = s2+b;
            int pi = pmap[aa][bb];
            if (pi < 0){ pi = npr; pmap[aa][bb] = pi;
                         tb.pairs[npr] = (aa*17) | ((bb*17)<<8); npr++; }
            tb.TD[(pi*30 + (slot-4))*8 + c] = (float)v;
          }
        }
      }
      tb.ccnt[slot*8+c] = cnt;
      tot += cnt;
    }
    for (int c=pt.kd;c<8;c++) tb.ccnt[slot*8+c]=0;
    tb.pmeta[slot*4+2] = tot;
    tb.pmeta[slot*4+3] = pt.kd;
  }
  if (npr & 1){ tb.pairs[npr] = 0; npr++; }   // pad to even -> Kdim % 32 == 0
  tb.npairs = npr;
  tb.npaths = np; tb.nent = ep; tb.tptot = tpoff;
}

} // namespace cgt

// ============================ device kernels ============================

enum GFlags { F_NONE=0, F_SILU=1, F_ENV=2, F_RESID=4 };

typedef __attribute__((ext_vector_type(8))) short bf16x8;
typedef __attribute__((ext_vector_type(4))) float f32x4;

__device__ inline unsigned short f2b(float f){
  union { float f; unsigned u; } x; x.f = f;
  unsigned r = (x.u + 0x7fffu + ((x.u >> 16) & 1u)) >> 16;
  return (unsigned short)r;
}

// XOR swizzle for 64B-row LDS tiles of bf16: 2-way (free) on ds_read_b128
// fragment loads. kh in ushort units (multiple of 4).
__device__ inline int swz(int row, int kh){
  int b = row*64 + kh*2;
  return b ^ (((row >> 1) & 3) << 4);
}

// ---- bf16 MFMA GEMM: C[M,N] = post( A[M,K] @ W[K,N] / sqrt(K) ), A fp32 ----
template<int FLAGS>
__global__ __launch_bounds__(256) void mgemm_k(
    const float* __restrict__ A1, const float* __restrict__ A2,
    int K1, int K, const unsigned short* __restrict__ Wt, int N,
    float* Cout, const float* __restrict__ env,
    const float* __restrict__ alphap, const float* Xres)
{
  __shared__ unsigned short AsB[128*32];
  __shared__ unsigned short BsB[128*32];
  const int tid  = threadIdx.x;
  const int wave = tid >> 6, lane = tid & 63;
  const int bm = blockIdx.x*128, bn = blockIdx.y*128;
  const int wr = (wave >> 1)*64, wc = (wave & 1)*64;
  const int K2 = K - K1;
  f32x4 acc[4][4] = {};

  const int sr  = tid >> 3;          // staging row 0..31 (A)
  const int skq = (tid & 7) * 4;     // staging k 0..28 step 4 (A)
  const int bn_ = tid >> 1;          // staging n 0..127 (B)
  const int bkh = (tid & 1) * 16;    // staging k half (B)

  for (int k0 = 0; k0 < K; k0 += 32) {
#pragma unroll
    for (int q = 0; q < 4; q++) {
      int row = q*32 + sr;
      int grow = bm + row;
      int kk = k0 + skq;
      float4 f4 = (kk < K1) ? *(const float4*)(A1 + (size_t)grow*K1 + kk)
                            : *(const float4*)(A2 + (size_t)grow*K2 + (kk - K1));
      ushort4 u;
      u.x = f2b(f4.x); u.y = f2b(f4.y); u.z = f2b(f4.z); u.w = f2b(f4.w);
      *(ushort4*)((char*)AsB + swz(row, skq)) = u;
    }
    {
      const unsigned short* s = Wt + (size_t)(bn + bn_)*K + k0 + bkh;
#pragma unroll
      for (int q = 0; q < 4; q++) {
        ushort4 u = *(const ushort4*)(s + q*4);
        *(ushort4*)((char*)BsB + swz(bn_, bkh + q*4)) = u;
      }
    }
    __syncthreads();
    const int fr = lane & 15, fk = (lane >> 4) * 8;
    bf16x8 af[4], bf[4];
#pragma unroll
    for (int i = 0; i < 4; i++)
      af[i] = *(bf16x8*)((char*)AsB + swz(wr + i*16 + fr, fk));
#pragma unroll
    for (int j = 0; j < 4; j++)
      bf[j] = *(bf16x8*)((char*)BsB + swz(wc + j*16 + fr, fk));
#pragma unroll
    for (int i = 0; i < 4; i++)
#pragma unroll
      for (int j = 0; j < 4; j++)
        acc[i][j] = __builtin_amdgcn_mfma_f32_16x16x32_bf16(af[i], bf[j], acc[i][j], 0, 0, 0);
    __syncthreads();
  }

  const float rscale = 1.f/sqrtf((float)K);
  float a2 = 0.f, inv1a2 = 1.f;
  if (FLAGS & F_RESID) { float al = alphap[0]; a2 = al*al; inv1a2 = 1.f/(1.f+a2); }
#pragma unroll
  for (int i = 0; i < 4; i++) {
#pragma unroll
    for (int r = 0; r < 4; r++) {
      int row = bm + wr + i*16 + ((lane >> 4) << 2) + r;
      float ev = (FLAGS & F_ENV) ? env[row] : 1.f;
#pragma unroll
      for (int j = 0; j < 4; j++) {
        int col = bn + wc + j*16 + (lane & 15);
        float v = acc[i][j][r]*rscale;
        if (FLAGS & F_SILU) v = v/(1.f+__expf(-v));
        if (FLAGS & F_ENV)  v *= ev;
        if (FLAGS & F_RESID) v = (Xres[(size_t)row*N+col] + a2*v)*inv1a2;
        Cout[(size_t)row*N+col] = v;
      }
    }
  }
}

// ---- Vn GEMM v2: Vn[eBase+rows, 256] = X[rows,K] @ Gt^T ----
// Tile 128 rows x 64 cols, 4 waves 2x2 (wave: 64r x 32c, 4x2 frags).
// grid.x = col-tile (fast; adjacent blocks share X rows -> L2),
// grid.y = row-tile. LDS 12 KB -> ~8 blocks/CU resident (R4 fix: was 224
// blocks total @ 1 wave/SIMD -> Occupancy 5.7%).
__global__ __launch_bounds__(256) void magemm_k(
    const unsigned short* __restrict__ X, const unsigned short* __restrict__ Gt,
    int K, float* __restrict__ Vn, int eBase)
{
  __shared__ unsigned short AsB[128*32];  // 8 KB
  __shared__ unsigned short BsB[64*32];   // 4 KB
  const int tid  = threadIdx.x;
  const int wave = tid >> 6, lane = tid & 63;
  const int bn = blockIdx.x * 64;
  const int bm = blockIdx.y * 128;
  const int wr = (wave >> 1) * 64;
  const int wc = (wave & 1) * 32;
  f32x4 acc[4][2] = {};
  const int sr  = tid >> 1;          // 0..127
  const int skh = (tid & 1) * 16;    // k half (16 ushorts)

  for (int k0 = 0; k0 < K; k0 += 32) {
    {
      const unsigned short* ap = X + (size_t)(bm + sr)*K + k0 + skh;
      uint4 u0 = *(const uint4*)ap;
      uint4 u1 = *(const uint4*)(ap + 8);
      *(uint4*)((char*)AsB + swz(sr, skh))     = u0;
      *(uint4*)((char*)AsB + swz(sr, skh + 8)) = u1;
    }
    if (tid < 128) {
      const unsigned short* bp = Gt + (size_t)(bn + sr)*K + k0 + skh;
      uint4 v0 = *(const uint4*)bp;
      uint4 v1 = *(const uint4*)(bp + 8);
      *(uint4*)((char*)BsB + swz(sr, skh))     = v0;
      *(uint4*)((char*)BsB + swz(sr, skh + 8)) = v1;
    }
    __syncthreads();
    const int fr = lane & 15, fk = (lane >> 4) * 8;
    bf16x8 af[4], bfr[2];
#pragma unroll
    for (int i = 0; i < 4; i++)
      af[i] = *(bf16x8*)((char*)AsB + swz(wr + i*16 + fr, fk));
#pragma unroll
    for (int j = 0; j < 2; j++)
      bfr[j] = *(bf16x8*)((char*)BsB + swz(wc + j*16 + fr, fk));
#pragma unroll
    for (int i = 0; i < 4; i++)
#pragma unroll
      for (int j = 0; j < 2; j++)
        acc[i][j] = __builtin_amdgcn_mfma_f32_16x16x32_bf16(af[i], bfr[j], acc[i][j], 0, 0, 0);
    __syncthreads();
  }
#pragma unroll
  for (int i = 0; i < 4; i++)
#pragma unroll
    for (int r = 0; r < 4; r++) {
      int row = eBase + bm + wr + i*16 + ((lane >> 4) << 2) + r;
#pragma unroll
      for (int j = 0; j < 2; j++) {
        int col = bn + wc + j*16 + (lane & 15);
        Vn[(size_t)row*256 + col] = acc[i][j][r];
      }
    }
}

// ---- X[e,(pair,m)] = (eps*node[s,m,a]) * V[e,m,b], bf16 ----
__global__ __launch_bounds__(256) void xbuild_k(
    const float* __restrict__ node, const float* __restrict__ V,
    const int* __restrict__ senders, const float* __restrict__ varepsp,
    const int* __restrict__ pairs, unsigned short* __restrict__ X,
    int eBase, int Kdim)
{
  __shared__ float As[272], Bs[272];
  const int e = eBase + blockIdx.x;
  const int tid = threadIdx.x;
  float ve = varepsp[0];
  float eps = rsqrtf(1.f + ve*ve);
  int s = senders[e];
  As[(tid & 15)*17 + (tid >> 4)] = node[((size_t)s << 8) + tid] * eps;
  Bs[(tid & 15)*17 + (tid >> 4)] = V[((size_t)e << 8) + tid];
  __syncthreads();
  size_t xrow = (size_t)blockIdx.x * Kdim;
  for (int idx = tid; idx < Kdim; idx += 256) {
    int pk = pairs[idx >> 4];
    int m = idx & 15;
    X[xrow + idx] = f2b(As[(pk & 255) + m] * Bs[((pk >> 8) & 255) + m]);
  }
}

// ---- Gt[col][k] = combined coupling x Wv matrix (bf16), col=(d,kabs) ----
__global__ void gbuild_k(const float* __restrict__ TD,
    const float* __restrict__ Wv1, const float* __restrict__ Wv2,
    const float* __restrict__ Wv3, const int* __restrict__ sl_origc,
    unsigned short* __restrict__ Gt, int Kdim, int npairs,
    int s1b, int s1e, int s2e, int s3e)
{
  int k = blockIdx.x*256 + threadIdx.x;
  if (k >= Kdim) return;
  int col = blockIdx.y;
  int pair = k >> 4, m = k & 15;
  int d = col >> 4, kabs = col & 15;
  float acc = 0.f;
  if (kabs > 0 && pair < npairs) {
    const float* Wv; int ss, se, kloc;
    if (kabs < 4)      { Wv = Wv1; ss = s1b; se = s1e; kloc = kabs - 1; }
    else if (kabs < 9) { Wv = Wv2; ss = s1e; se = s2e; kloc = kabs - 4; }
    else               { Wv = Wv3; ss = s2e; se = s3e; kloc = kabs - 9; }
    for (int slot = ss; slot < se; slot++)
      acc += TD[((pair*30) + (slot - 4))*8 + kloc] * Wv[(sl_origc[slot] + m)*16 + d];
    acc *= rsqrtf((float)(16*(se - ss)));
  }
  Gt[(size_t)col*Kdim + k] = f2b(acc);
}

// ---- weight convert + transpose: Wt[n][k] = bf16(W[k][n]) ----
struct WDesc { const float* src; unsigned short* dst; int K; int lgN; };
struct WPack { WDesc d[9]; };
__global__ void wcvt_k(WPack p){
  WDesc d = p.d[blockIdx.y];
  int total = d.K << d.lgN;
  int gid = blockIdx.x*256 + threadIdx.x;
  if (gid >= total) return;
  int k = gid >> d.lgN, n = gid & ((1 << d.lgN) - 1);
  d.dst[(size_t)n*d.K + k] = f2b(d.src[gid]);
}

// Generic fp32 tiled GEMM (small two-body layers).
template<int FLAGS>
__global__ __launch_bounds__(256) void gemm_k(
    const float* __restrict__ A1, const float* __restrict__ A2,
    int K1, int K, const float* __restrict__ W, int N,
    float* Cout,
    const float* __restrict__ env, const float* __restrict__ alphap,
    const float* Xres)
{
  __shared__ float As[16][68];
  __shared__ float Ws[16][68];
  const int tid = threadIdx.x;
  const int bm = blockIdx.x * 64;
  const int bn = blockIdx.y * 64;
  const int tx = tid & 15, ty = tid >> 4;
  const int K2 = K - K1;
  float acc[4][4] = {};
  for (int k0 = 0; k0 < K; k0 += 16) {
#pragma unroll
    for (int i = 0; i < 4; i++) {
      int idx = tid + i*256;
      int m = idx >> 4, kk = idx & 15;
      int k = k0 + kk;
      float v = 0.f;
      if (k < K) {
        int row = bm + m;
        v = (k < K1) ? A1[(size_t)row*K1 + k] : A2[(size_t)row*K2 + (k-K1)];
      }
      As[kk][m] = v;
    }
#pragma unroll
    for (int i = 0; i < 4; i++) {
      int idx = tid + i*256;
      int n = idx & 63, kk = idx >> 6;
      int k = k0 + kk, col = bn + n;
      Ws[kk][n] = (k < K && col < N) ? W[(size_t)k*N + col] : 0.f;
    }
    __syncthreads();
#pragma unroll
    for (int kk = 0; kk < 16; kk++) {
      float a[4], b[4];
#pragma unroll
      for (int i=0;i<4;i++) a[i] = As[kk][ty*4+i];
#pragma unroll
      for (int j=0;j<4;j++) b[j] = Ws[kk][tx*4+j];
#pragma unroll
      for (int i=0;i<4;i++)
#pragma unroll
        for (int j=0;j<4;j++)
          acc[i][j] += a[i]*b[j];
    }
    __syncthreads();
  }
  const float rscale = 1.f/sqrtf((float)K);
  float a2 = 0.f, inv1a2 = 1.f;
  if (FLAGS & F_RESID) { float al = alphap[0]; a2 = al*al; inv1a2 = 1.f/(1.f+a2); }
#pragma unroll
  for (int i=0;i<4;i++) {
    int row = bm + ty*4 + i;
    float ev = (FLAGS & F_ENV) ? env[row] : 1.f;
#pragma unroll
    for (int j=0;j<4;j++) {
      int col = bn + tx*4 + j;
      if (col >= N) continue;
      float v = acc[i][j]*rscale;
      if (FLAGS & F_SILU) v = v/(1.f+__expf(-v));
      if (FLAGS & F_ENV)  v *= ev;
      if (FLAGS & F_RESID) v = (Xres[(size_t)row*N+col] + a2*v)*inv1a2;
      Cout[(size_t)row*N+col] = v;
    }
  }
}

// dense to 16 outputs, K=256 fixed, scale 1/16
__global__ __launch_bounds__(256) void dense16_k(const float* __restrict__ A,
    const float* __restrict__ W, float* __restrict__ C)
{
  __shared__ float As[16*256];
  const int r0 = blockIdx.x << 4;
  const int tid = threadIdx.x;
  for (int i = tid; i < 16*256; i += 256)
    As[i] = A[((size_t)r0<<8) + i];
  __syncthreads();
  const int r = tid >> 4, n = tid & 15;
  float acc = 0.f;
#pragma unroll 8
  for (int k = 0; k < 256; k++)
    acc += As[(r<<8)+k] * W[(k<<4)+n];
  C[((size_t)(r0+r)<<4)+n] = acc * 0.0625f;
}

__global__ void edge_init_k(const float* __restrict__ vectors, const int* __restrict__ senders,
    const int* __restrict__ receivers, const int* __restrict__ species,
    const float* __restrict__ emb, float* __restrict__ envb, float* __restrict__ Yb,
    float* __restrict__ x72)
{
  const int e = blockIdx.x*256 + threadIdx.x;
  float vx = vectors[e*3+0], vy = vectors[e*3+1], vz = vectors[e*3+2];
  float d = sqrtf(vx*vx+vy*vy+vz*vz);
  float dd = (d==0.f) ? 1.f : d;
  float invd = 1.f/dd;
  float x = vx*invd, y = vy*invd, z = vz*invd;
  float d2=d*d, d3=d2*d, d6=d3*d3, d7=d6*d, d8=d7*d;
  float envv = (d<1.f) ? (1.f - 28.f*d6 + 48.f*d7 - 21.f*d8) : 0.f;
  envb[e] = envv;
  float mask = (d==0.f)?0.f:1.f;
  const float SQ2 = 1.41421356237309515f;
  const float PIf = 3.14159265358979323846f;
  float* xr = x72 + (size_t)e*72;
#pragma unroll
  for (int n=1;n<=8;n++)
    xr[n-1] = SQ2 * sinf((float)n*PIf*dd)*invd*envv*mask;
  int sp_s = species[senders[e]], sp_r = species[receivers[e]];
  const float* es_ = emb + (size_t)sp_s*32;
  const float* er_ = emb + (size_t)sp_r*32;
#pragma unroll 8
  for (int k=0;k<32;k++){ xr[8+k] = es_[k]*mask; xr[40+k] = er_[k]*mask; }
  float x2=x*x, y2=y*y, z2=z*z;
  const float s3=1.7320508075688772f, s15=3.872983346207417f, s5=2.23606797749979f;
  const float s358=2.0916500663351889f, s105=10.246950765959598f;
  const float s218=1.6201851746019651f, s7=2.6457513110645907f;
  float* Yr = Yb + ((size_t)e<<4);
  Yr[0]=1.f;           Yr[1]=s3*y;          Yr[2]=s3*z;           Yr[3]=s3*x;
  Yr[4]=s15*x*y;       Yr[5]=s15*y*z;       Yr[6]=0.5f*s5*(3.f*z2-1.f);
  Yr[7]=s15*x*z;       Yr[8]=0.5f*s15*(x2-y2);
  Yr[9]=s358*y*(3.f*x2-y2);  Yr[10]=s105*x*y*z;  Yr[11]=s218*y*(5.f*z2-1.f);
  Yr[12]=0.5f*s7*(5.f*z2-3.f)*z;  Yr[13]=s218*x*(5.f*z2-1.f);
  Yr[14]=0.5f*s105*(x2-y2)*z;     Yr[15]=s358*x*(x2-y2);
}

// V[e,m,k] = w0[e,m]*Y[e,k]
__global__ void vinit_k(const float* __restrict__ w0, const float* __restrict__ Y,
                        float* __restrict__ V)
{
  const int gid = blockIdx.x*256 + threadIdx.x;
  const int e = gid >> 8, idx = gid & 255;
  V[gid] = w0[(e<<4)+(idx>>4)] * Y[(e<<4)+(idx&15)];
}

// node[senders[e], m, k] += w[e,m]*Y[e,k]
__global__ void scatter_k(const float* __restrict__ w, const float* __restrict__ Y,
                          const int* __restrict__ senders, float* node)
{
  const int gid = blockIdx.x*256 + threadIdx.x;
  const int e = gid >> 8, idx = gid & 255;
  float v = w[(e<<4) + (idx>>4)] * Y[(e<<4) + (idx&15)];
  atomicAdd(&node[((size_t)senders[e]<<8) + idx], v);
}

// l3=0 TP (slots 0..3), one thread per (e, p*16+m). B = V (layer1) or Vn (layer2).
__global__ void tp2_k(const float* __restrict__ node, const float* __restrict__ Vn,
    const int* __restrict__ senders, const float* __restrict__ varepsp,
    const int* __restrict__ pmeta, const int* __restrict__ entIJ,
    const float* __restrict__ entVal, float* __restrict__ tp0)
{
  const int gid = blockIdx.x*256 + threadIdx.x;
  const int e = gid >> 6, c = gid & 63;
  const int p = c >> 4, m = c & 15;
  float ve = varepsp[0];
  float eps = rsqrtf(1.f + ve*ve);
  int s = senders[e];
  const float* Am = &node[((size_t)s<<8) + (m<<4)];
  const float* Bm = &Vn[((size_t)e<<8) + (m<<4)];
  int es = pmeta[p*4+1], ec = pmeta[p*4+2];
  float acc = 0.f;
  for (int t=0;t<ec;t++){
    int ij = entIJ[es+t];
    acc += entVal[es+t] * Am[ij&255] * Bm[(ij>>8)&255];
  }
  tp0[((size_t)e<<6) + pmeta[p*4+0] + m] = acc * eps;
}

// out[e] = env[e] * dot(X[e,:128], Wout) / sqrt(128)
__global__ void final_k(const float* __restrict__ X, const float* __restrict__ Wout,
                        const float* __restrict__ env, float* __restrict__ out)
{
  const int e = blockIdx.x*256 + threadIdx.x;
  float acc = 0.f;
#pragma unroll 16
  for (int k=0;k<128;k++) acc += X[((size_t)e<<7)+k]*Wout[k];
  out[e] = env[e]*acc*0.088388347648318447f;
}

// ============================ host launcher ============================

static void launch_gemm(int flags, const float* A1, const float* A2, int K1, int K,
    const float* W, int N, float* C, const float* env, const float* alphap,
    const float* Xres, hipStream_t stream)
{
  dim3 grid(E_EDGES/64, (N+63)/64);
  switch(flags){
    case F_NONE:        gemm_k<F_NONE>       <<<grid,256,0,stream>>>(A1,A2,K1,K,W,N,C,env,alphap,Xres); break;
    case F_SILU:        gemm_k<F_SILU>       <<<grid,256,0,stream>>>(A1,A2,K1,K,W,N,C,env,alphap,Xres); break;
    case F_ENV:         gemm_k<F_ENV>        <<<grid,256,0,stream>>>(A1,A2,K1,K,W,N,C,env,alphap,Xres); break;
    case F_ENV|F_RESID: gemm_k<F_ENV|F_RESID><<<grid,256,0,stream>>>(A1,A2,K1,K,W,N,C,env,alphap,Xres); break;
  }
}

static void launch_mgemm(int flags, const float* A1, const float* A2, int K1, int K,
    const unsigned short* Wt, int N, float* C, const float* env, const float* alphap,
    const float* Xres, hipStream_t stream)
{
  dim3 grid(E_EDGES/128, N/128);
  switch(flags){
    case F_NONE:        mgemm_k<F_NONE>       <<<grid,256,0,stream>>>(A1,A2,K1,K,Wt,N,C,env,alphap,Xres); break;
    case F_SILU:        mgemm_k<F_SILU>       <<<grid,256,0,stream>>>(A1,A2,K1,K,Wt,N,C,env,alphap,Xres); break;
    case F_ENV:         mgemm_k<F_ENV>        <<<grid,256,0,stream>>>(A1,A2,K1,K,Wt,N,C,env,alphap,Xres); break;
    case F_ENV|F_RESID: mgemm_k<F_ENV|F_RESID><<<grid,256,0,stream>>>(A1,A2,K1,K,Wt,N,C,env,alphap,Xres); break;
  }
}

extern "C" void kernel_launch(void* const* d_in, const int* in_sizes, int n_in,
                              void* d_out, int out_size, void* d_ws, size_t ws_size,
                              hipStream_t stream)
{
  const float* vectors = (const float*)d_in[0];
  const float* vareps  = (const float*)d_in[1];
  const float* alpha   = (const float*)d_in[2];
  const float* emb     = (const float*)d_in[3];
  const float* W_tb1   = (const float*)d_in[4];
  const float* W_tb2   = (const float*)d_in[5];
  const float* W_tb3   = (const float*)d_in[6];
  const float* W_tb4   = (const float*)d_in[7];
  const float* W_w0    = (const float*)d_in[8];
  const float* W_w1    = (const float*)d_in[9];
  const float* W_l11   = (const float*)d_in[10];
  const float* W_l12   = (const float*)d_in[11];
  const float* W_l13   = (const float*)d_in[12];
  const float* W_v1    = (const float*)d_in[13];
  const float* W_v2    = (const float*)d_in[14];
  const float* W_v3    = (const float*)d_in[15];
  const float* W_w2    = (const float*)d_in[16];
  const float* W_l21   = (const float*)d_in[17];
  const float* W_l22   = (const float*)d_in[18];
  const float* W_l23   = (const float*)d_in[19];
  const float* W_h     = (const float*)d_in[20];
  const float* W_out   = (const float*)d_in[21];
  const int* senders   = (const int*)d_in[22];
  const int* receivers = (const int*)d_in[23];
  const int* species   = (const int*)d_in[24];

  static cgt::Tables tb;
  cgt::build(tb);
  const int Kdim = tb.npairs * 16;

  char* ws = (char*)d_ws;
  size_t off = 0;
  auto alloc = [&](size_t bytes)->void*{
    void* p = ws + off; off += (bytes + 255) & ~(size_t)255; return p;
  };
  float* t_val = (float*)alloc(sizeof(tb.val));
  int*   t_ij  = (int*)  alloc(sizeof(tb.ij));
  int*   t_pm  = (int*)  alloc(sizeof(tb.pmeta));
  float* t_td  = (float*)alloc(sizeof(tb.TD));
  int*   t_pr  = (int*)  alloc(sizeof(tb.pairs));
  int*   t_oc  = (int*)  alloc(sizeof(tb.sl_origc));
  float* envb  = (float*)alloc((size_t)E_EDGES*4);
  float* Yb    = (float*)alloc((size_t)E_EDGES*16*4);
  float* xb    = (float*)alloc((size_t)E_EDGES*256*4);
  float* Vb    = (float*)alloc((size_t)E_EDGES*256*4);   // V, then Vn (in-place)
  // --- window (X overlays bufA..wb while they are dead) ---
  float* bufA  = (float*)alloc((size_t)E_EDGES*256*4);
  float* bufB  = (float*)alloc((size_t)E_EDGES*256*4);
  float* wb    = (float*)alloc((size_t)E_EDGES*16*4);
  size_t winBytes = (size_t)E_EDGES*256*4*2 + (size_t)E_EDGES*16*4;
  // ---------------------------------------------------------
  float* tp0b  = (float*)alloc((size_t)E_EDGES*64*4);
  float* nodeb = (float*)alloc((size_t)NNODES*256*4);
  unsigned short* Gt = (unsigned short*)alloc((size_t)256*Kdim*2);
  unsigned short* Wt_tb3 = (unsigned short*)alloc(64*128*2);
  unsigned short* Wt_tb4 = (unsigned short*)alloc(128*256*2);
  unsigned short* Wt_l11 = (unsigned short*)alloc(320*256*2);
  unsigned short* Wt_l12 = (unsigned short*)alloc(256*256*2);
  unsigned short* Wt_l13 = (unsigned short*)alloc(256*256*2);
  unsigned short* Wt_l21 = (unsigned short*)alloc(320*256*2);
  unsigned short* Wt_l22 = (unsigned short*)alloc(256*256*2);
  unsigned short* Wt_l23 = (unsigned short*)alloc(256*256*2);
  unsigned short* Wt_h   = (unsigned short*)alloc(256*128*2);
  if (off > ws_size) {
    fprintf(stderr, "[allegro] workspace too small: need %zu, have %zu\n", off, ws_size);
    return;
  }
  unsigned short* Xbuf = (unsigned short*)bufA;
  int chunkE = (int)((winBytes / ((size_t)Kdim*2)) & ~(size_t)127);
  if (chunkE > E_EDGES) chunkE = E_EDGES;

  hipMemcpyAsync(t_val, tb.val,     sizeof(tb.val),     hipMemcpyHostToDevice, stream);
  hipMemcpyAsync(t_ij,  tb.ij,      sizeof(tb.ij),      hipMemcpyHostToDevice, stream);
  hipMemcpyAsync(t_pm,  tb.pmeta,   sizeof(tb.pmeta),   hipMemcpyHostToDevice, stream);
  hipMemcpyAsync(t_td,  tb.TD,      sizeof(tb.TD),      hipMemcpyHostToDevice, stream);
  hipMemcpyAsync(t_pr,  tb.pairs,   sizeof(tb.pairs),   hipMemcpyHostToDevice, stream);
  hipMemcpyAsync(t_oc,  tb.sl_origc,sizeof(tb.sl_origc),hipMemcpyHostToDevice, stream);

  // slot ranges (l3 blocks contiguous in slot order): l1: [s1b,s1e) etc.
  const int s1b = tb.l3np[0];
  const int s1e = s1b + tb.l3np[1];
  const int s2e = s1e + tb.l3np[2];
  const int s3e = s2e + tb.l3np[3];

  // combined coupling x Wv matrix
  {
    dim3 g((Kdim + 255)/256, 256);
    gbuild_k<<<g, 256, 0, stream>>>(t_td, W_v1, W_v2, W_v3, t_oc, Gt, Kdim,
                                    tb.npairs, s1b, s1e, s2e, s3e);
  }
  // weight convert+transpose (bf16)
  {
    WPack p;
    p.d[0] = { W_tb3, Wt_tb3,  64, 7 };
    p.d[1] = { W_tb4, Wt_tb4, 128, 8 };
    p.d[2] = { W_l11, Wt_l11, 320, 8 };
    p.d[3] = { W_l12, Wt_l12, 256, 8 };
    p.d[4] = { W_l13, Wt_l13, 256, 8 };
    p.d[5] = { W_l21, Wt_l21, 320, 8 };
    p.d[6] = { W_l22, Wt_l22, 256, 8 };
    p.d[7] = { W_h,   Wt_h,   256, 7 };
    p.d[8] = { W_l23, Wt_l23, 256, 8 };
    dim3 g(320, 9);
    wcvt_k<<<g, 256, 0, stream>>>(p);
  }

  // 1. edge features + Y + env
  edge_init_k<<<E_EDGES/256, 256, 0, stream>>>(vectors, senders, receivers, species,
                                               emb, envb, Yb, bufA);
  // 2. two-body MLP: 72 -> 32 -> 64 (fp32) -> 128 -> 256 (bf16 MFMA)
  launch_gemm (F_SILU, bufA, nullptr, 72, 72,  W_tb1, 32,   bufB, envb, alpha, nullptr, stream);
  launch_gemm (F_SILU, bufB, nullptr, 32, 32,  W_tb2, 64,   bufA, envb, alpha, nullptr, stream);
  launch_mgemm(F_SILU, bufA, nullptr, 64, 64,  Wt_tb3, 128, bufB, envb, alpha, nullptr, stream);
  launch_mgemm(F_ENV,  bufB, nullptr, 128,128, Wt_tb4, 256, xb,   envb, alpha, nullptr, stream);
  // 3. V = dense(x,W_w0) outer Y
  dense16_k<<<E_EDGES/16, 256, 0, stream>>>(xb, W_w0, wb);
  vinit_k<<<E_EDGES, 256, 0, stream>>>(wb, Yb, Vb);

  // ---- layer 1 ----
  dense16_k<<<E_EDGES/16, 256, 0, stream>>>(xb, W_w1, wb);
  hipMemsetAsync(nodeb, 0, (size_t)NNODES*256*4, stream);
  scatter_k<<<E_EDGES, 256, 0, stream>>>(wb, Yb, senders, nodeb);
  // tp0 (l3=0) exact fp32; B = V
  tp2_k<<<E_EDGES*64/256, 256, 0, stream>>>(nodeb, Vb, senders, vareps, t_pm, t_ij,
                                            t_val, tp0b);
  // Vn via fused pair-product GEMM (chunked through the dead bufA..wb window)
  for (int eb = 0; eb < E_EDGES; eb += chunkE) {
    int n = E_EDGES - eb; if (n > chunkE) n = chunkE;
    xbuild_k<<<n, 256, 0, stream>>>(nodeb, Vb, senders, vareps, t_pr, Xbuf, eb, Kdim);
    dim3 g(4, n/128);   // col-tile fast -> L2 sharing of X rows
    magemm_k<<<g, 256, 0, stream>>>(Xbuf, Gt, Kdim, Vb, eb);
  }
  launch_mgemm(F_SILU,        xb,   tp0b,   256, 320, Wt_l11, 256, bufB, envb, alpha, nullptr, stream);
  launch_mgemm(F_SILU,        bufB, nullptr,256, 256, Wt_l12, 256, bufA, envb, alpha, nullptr, stream);
  launch_mgemm(F_ENV|F_RESID, bufA, nullptr,256, 256, Wt_l13, 256, xb,   envb, alpha, xb,      stream);

  // ---- layer 2 (lmax_out = 0) ----
  dense16_k<<<E_EDGES/16, 256, 0, stream>>>(xb, W_w2, wb);
  hipMemsetAsync(nodeb, 0, (size_t)NNODES*256*4, stream);
  scatter_k<<<E_EDGES, 256, 0, stream>>>(wb, Yb, senders, nodeb);
  tp2_k<<<E_EDGES*64/256, 256, 0, stream>>>(nodeb, Vb, senders, vareps, t_pm, t_ij,
                                            t_val, tp0b);
  launch_mgemm(F_SILU,        xb,   tp0b,   256, 320, Wt_l21, 256, bufB, envb, alpha, nullptr, stream);
  launch_mgemm(F_SILU,        bufB, nullptr,256, 256, Wt_l22, 256, bufA, envb, alpha, nullptr, stream);
  launch_mgemm(F_ENV|F_RESID, bufA, nullptr,256, 256, Wt_l23, 256, xb,   envb, alpha, xb,      stream);

  // ---- head ----
  launch_mgemm(F_NONE, xb, nullptr, 256, 256, Wt_h, 128, bufB, envb, alpha, nullptr, stream);
  final_k<<<E_EDGES/256, 256, 0, stream>>>(bufB, W_out, envb, (float*)d_out);
}

// Round 6
// 705.900 us; speedup vs baseline: 1.4696x; 1.4696x over previous
//
#include <hip/hip_runtime.h>
#include <cmath>
#include <complex>
#include <cstdio>
#include <cstring>
#include <algorithm>

#define E_EDGES 32768
#define NNODES  2048
#define VN_E    32      // edges per vn_k block

// ============================ host-side CG tables ============================
namespace cgt {

static double fct(int n){
  static const double f[13] = {1.,1.,2.,6.,24.,120.,720.,5040.,40320.,362880.,
                               3628800.,39916800.,479001600.};
  return f[n];
}

static double cg(int j1,int m1,int j2,int m2,int j3,int m3){
  if (m1+m2 != m3) return 0.0;
  double pre = std::sqrt((2*j3+1)*fct(j1+j2-j3)*fct(j1-j2+j3)*fct(-j1+j2+j3)/fct(j1+j2+j3+1));
  pre *= std::sqrt(fct(j3+m3)*fct(j3-m3)*fct(j1-m1)*fct(j1+m1)*fct(j2-m2)*fct(j2+m2));
  int kmin = 0;
  if (j2-j3-m1 > kmin) kmin = j2-j3-m1;
  if (j1-j3+m2 > kmin) kmin = j1-j3+m2;
  int kmax = j1+j2-j3;
  if (j1-m1 < kmax) kmax = j1-m1;
  if (j2+m2 < kmax) kmax = j2+m2;
  double s = 0.0;
  for (int k=kmin;k<=kmax;k++){
    double d = fct(k)*fct(j1+j2-j3-k)*fct(j1-m1-k)*fct(j2+m2-k)*fct(j3-j2+m1+k)*fct(j3-j1-m2+k);
    s += ((k&1)? -1.0:1.0)/d;
  }
  return pre*s;
}

typedef std::complex<double> cd;

static void umat(int l, cd U[7][7]){
  for (int a=0;a<7;a++) for (int b=0;b<7;b++) U[a][b]=cd(0,0);
  U[l][l] = cd(1,0);
  double s2 = 1.0/std::sqrt(2.0);
  for (int m=1;m<=l;m++){
    double sg = (m&1)? -1.0 : 1.0;
    U[l+m][l-m] = cd(s2,0);
    U[l+m][l+m] = cd(sg*s2,0);
    U[l-m][l-m] = cd(0, s2);
    U[l-m][l+m] = cd(0, -sg*s2);
  }
}

static bool realCoupling(int l1,int l2,int l3, double T[7][7][7]){
  cd U1[7][7],U2[7][7],U3[7][7];
  umat(l1,U1); umat(l2,U2); umat(l3,U3);
  int n1=2*l1+1, n2=2*l2+1, n3=2*l3+1;
  double Cg[7][7][7];
  for (int m=0;m<n1;m++) for(int n=0;n<n2;n++) for(int k=0;k<n3;k++)
    Cg[m][n][k] = cg(l1,m-l1,l2,n-l2,l3,k-l3);
  double Tr[7][7][7], Ti[7][7][7];
  double nr=0, ni=0;
  for (int a=0;a<n1;a++) for(int b=0;b<n2;b++) for(int c=0;c<n3;c++){
    cd s(0,0);
    for (int m=0;m<n1;m++){
      if (U1[a][m]==cd(0,0)) continue;
      for (int n=0;n<n2;n++){
        if (U2[b][n]==cd(0,0)) continue;
        for (int k=0;k<n3;k++){
          double cgv = Cg[m][n][k];
          if (cgv==0.0) continue;
          s += U1[a][m]*U2[b][n]*std::conj(U3[c][k])*cgv;
        }
      }
    }
    Tr[a][b][c]=s.real(); Ti[a][b][c]=s.imag();
    nr += s.real()*s.real(); ni += s.imag()*s.imag();
  }
  bool useR = (nr >= ni);
  double nn = std::sqrt(useR? nr : ni);
  if (nn < 1e-8) return false;
  for (int a=0;a<n1;a++)for(int b=0;b<n2;b++)for(int c=0;c<n3;c++)
    T[a][b][c] = (useR? Tr[a][b][c] : Ti[a][b][c])/nn;
  return true;
}

struct Tables {
  float val[4096];
  int   ij[4096];        // (a_abs) | (b_abs<<8), entries grouped by (path, c)
  int   pmeta[40*4];     // per SLOT: tpOff(orig layout), entStart, entCount, kdim
  int   ccnt[40*8];      // per SLOT: entry count for each c (kd <= 7)
  int   l3base[4];
  int   l3np[4];
  int   npaths;
  int   nent;
  int   tptot;
  // --- pair/TD tables for the fused Vn GEMM (l>=1 slots only) ---
  int   pairs[256];      // raw (a_abs) | (b_abs<<8)
  float TD[256*30*8];    // TD[pair][slot-4][kloc] = T*sqrt(2l3+1)
  int   sl_origc[40];    // per slot: original c-base (origIdxInL*16) for Wv rows
  int   npairs;          // padded even
};

struct PathTmp {
  int l1,l2,l3, tpoff, kd;
  int ec;                 // total nonzero entries
  double T[7][7][7];
};

static void build(Tables& tb){
  static PathTmp paths[40];
  int np = 0, tpoff = 0;
  int l3start[5];
  for (int l3=0;l3<=3;l3++){
    tb.l3base[l3] = tpoff;
    l3start[l3] = np;
    int kd = 2*l3+1;
    for (int l1=0;l1<=3;l1++) for (int l2=0;l2<=3;l2++){
      int lo = (l1>l2)? l1-l2 : l2-l1;
      int hi = std::min(l1+l2,3);
      if (l3 < lo || l3 > hi) continue;
      PathTmp& pt = paths[np];
      if (!realCoupling(l1,l2,l3,pt.T)) continue;
      pt.l1=l1; pt.l2=l2; pt.l3=l3; pt.kd=kd; pt.tpoff=tpoff;
      double scale = std::sqrt((double)kd);
      int cnt = 0;
      for (int a=0;a<2*l1+1;a++)for(int b=0;b<2*l2+1;b++)for(int c=0;c<kd;c++)
        if (std::fabs(pt.T[a][b][c]*scale) > 1e-7) cnt++;
      pt.ec = cnt;
      tpoff += 16*kd;
      np++;
    }
  }
  l3start[4] = np;
  for (int l3=0;l3<=3;l3++) tb.l3np[l3] = l3start[l3+1]-l3start[l3];
  static int order[40];
  for (int i=0;i<np;i++) order[i]=i;
  for (int l3=0;l3<=3;l3++)
    std::sort(order+l3start[l3], order+l3start[l3+1],
              [&](int a,int b){ return paths[a].ec > paths[b].ec; });
  // emit entries grouped by (slot, c); build pair map + TD for l>=1 slots
  std::memset(tb.TD, 0, sizeof(tb.TD));
  std::memset(tb.pairs, 0, sizeof(tb.pairs));
  static int pmap[16][16];
  for (int i=0;i<16;i++) for (int j=0;j<16;j++) pmap[i][j] = -1;
  int npr = 0;
  int ep = 0;
  for (int slot=0; slot<np; slot++){
    const PathTmp& pt = paths[order[slot]];
    double scale = std::sqrt((double)pt.kd);
    int s1 = pt.l1*pt.l1, s2 = pt.l2*pt.l2;
    tb.pmeta[slot*4+0] = pt.tpoff;
    tb.pmeta[slot*4+1] = ep;
    tb.sl_origc[slot] = ((pt.tpoff - tb.l3base[pt.l3]) / (16*pt.kd)) * 16;
    int tot = 0;
    for (int c=0;c<pt.kd;c++){
      int cnt = 0;
      for (int a=0;a<2*pt.l1+1;a++)for(int b=0;b<2*pt.l2+1;b++){
        double v = pt.T[a][b][c]*scale;
        if (std::fabs(v) > 1e-7){
          tb.val[ep] = (float)v;
          tb.ij[ep]  = (s1+a) | ((s2+b)<<8);
          ep++; cnt++;
          if (pt.l3 >= 1){
            int aa = s1+a, bb = s2+b;
            int pi = pmap[aa][bb];
            if (pi < 0){ pi = npr; pmap[aa][bb] = pi;
                         tb.pairs[npr] = aa | (bb<<8); npr++; }
            tb.TD[(pi*30 + (slot-4))*8 + c] = (float)v;
          }
        }
      }
      tb.ccnt[slot*8+c] = cnt;
      tot += cnt;
    }
    for (int c=pt.kd;c<8;c++) tb.ccnt[slot*8+c]=0;
    tb.pmeta[slot*4+2] = tot;
    tb.pmeta[slot*4+3] = pt.kd;
  }
  if (npr & 1){ tb.pairs[npr] = 0; npr++; }   // pad to even -> Kdim % 32 == 0
  tb.npairs = npr;
  tb.npaths = np; tb.nent = ep; tb.tptot = tpoff;
}

} // namespace cgt

// ============================ device kernels ============================

enum GFlags { F_NONE=0, F_SILU=1, F_ENV=2, F_RESID=4 };

typedef _Float16 half8 __attribute__((ext_vector_type(8)));
typedef __attribute__((ext_vector_type(4))) float f32x4;

__device__ inline unsigned short f2h(float f){
  union { _Float16 h; unsigned short u; } x;
  x.h = (_Float16)f;           // v_cvt_f16_f32, RNE
  return x.u;
}
__device__ inline float h2f(unsigned short u){
  union { _Float16 h; unsigned short u; } x; x.u = u;
  return (float)x.h;
}

// XOR swizzle for 64B-row LDS tiles of 16-bit data: permutes 16B units so
// ds_read_b128 fragment loads are ~conflict-free. kh in ushort units (mult of 4).
__device__ inline int swz(int row, int kh){
  int b = row*64 + kh*2;
  return b ^ (((row >> 1) & 3) << 4);
}

// ---- fp16 MFMA GEMM: C[M,N] = post( A[M,K] @ W[K,N] / sqrt(K) ), A fp32 ----
template<int FLAGS>
__global__ __launch_bounds__(256) void mgemm_k(
    const float* __restrict__ A1, const float* __restrict__ A2,
    int K1, int K, const unsigned short* __restrict__ Wt, int N,
    float* Cout, const float* __restrict__ env,
    const float* __restrict__ alphap, const float* Xres)
{
  __shared__ unsigned short AsB[128*32];
  __shared__ unsigned short BsB[128*32];
  const int tid  = threadIdx.x;
  const int wave = tid >> 6, lane = tid & 63;
  const int bm = blockIdx.x*128, bn = blockIdx.y*128;
  const int wr = (wave >> 1)*64, wc = (wave & 1)*64;
  const int K2 = K - K1;
  f32x4 acc[4][4] = {};

  const int sr  = tid >> 3;          // staging row 0..31 (A)
  const int skq = (tid & 7) * 4;     // staging k 0..28 step 4 (A)
  const int bn_ = tid >> 1;          // staging n 0..127 (B)
  const int bkh = (tid & 1) * 16;    // staging k half (B)

  for (int k0 = 0; k0 < K; k0 += 32) {
#pragma unroll
    for (int q = 0; q < 4; q++) {
      int row = q*32 + sr;
      int grow = bm + row;
      int kk = k0 + skq;
      float4 f4 = (kk < K1) ? *(const float4*)(A1 + (size_t)grow*K1 + kk)
                            : *(const float4*)(A2 + (size_t)grow*K2 + (kk - K1));
      ushort4 u;
      u.x = f2h(f4.x); u.y = f2h(f4.y); u.z = f2h(f4.z); u.w = f2h(f4.w);
      *(ushort4*)((char*)AsB + swz(row, skq)) = u;
    }
    {
      const unsigned short* s = Wt + (size_t)(bn + bn_)*K + k0 + bkh;
#pragma unroll
      for (int q = 0; q < 4; q++) {
        ushort4 u = *(const ushort4*)(s + q*4);
        *(ushort4*)((char*)BsB + swz(bn_, bkh + q*4)) = u;
      }
    }
    __syncthreads();
    const int fr = lane & 15, fk = (lane >> 4) * 8;
    half8 af[4], bf[4];
#pragma unroll
    for (int i = 0; i < 4; i++)
      af[i] = *(half8*)((char*)AsB + swz(wr + i*16 + fr, fk));
#pragma unroll
    for (int j = 0; j < 4; j++)
      bf[j] = *(half8*)((char*)BsB + swz(wc + j*16 + fr, fk));
#pragma unroll
    for (int i = 0; i < 4; i++)
#pragma unroll
      for (int j = 0; j < 4; j++)
        acc[i][j] = __builtin_amdgcn_mfma_f32_16x16x32_f16(af[i], bf[j], acc[i][j], 0, 0, 0);
    __syncthreads();
  }

  const float rscale = 1.f/sqrtf((float)K);
  float a2 = 0.f, inv1a2 = 1.f;
  if (FLAGS & F_RESID) { float al = alphap[0]; a2 = al*al; inv1a2 = 1.f/(1.f+a2); }
#pragma unroll
  for (int i = 0; i < 4; i++) {
#pragma unroll
    for (int r = 0; r < 4; r++) {
      int row = bm + wr + i*16 + ((lane >> 4) << 2) + r;
      float ev = (FLAGS & F_ENV) ? env[row] : 1.f;
#pragma unroll
      for (int j = 0; j < 4; j++) {
        int col = bn + wc + j*16 + (lane & 15);
        float v = acc[i][j][r]*rscale;
        if (FLAGS & F_SILU) v = v/(1.f+__expf(-v));
        if (FLAGS & F_ENV)  v *= ev;
        if (FLAGS & F_RESID) v = (Xres[(size_t)row*N+col] + a2*v)*inv1a2;
        Cout[(size_t)row*N+col] = v;
      }
    }
  }
}

// ---- fused Vn kernel: per 32 edges, compute X slab on the fly + MFMA ----
// Vn[e, d*16+kabs] = sum_k X[e,k] * G[k, col];  X[(pair,m)] = (eps*node[s,m,a])*V[e,m,b]
// X never touches HBM (R5 fix: magemm FETCH 137MB/dispatch re-reading X).
// LDS ~52 KB -> 3 blocks/CU. fp16 operands (error < bf16 path).
__global__ __launch_bounds__(256) void vn_k(
    const float* __restrict__ node, const float* __restrict__ V,
    const int* __restrict__ senders, const float* __restrict__ varepsp,
    const int* __restrict__ pairsG, const unsigned short* __restrict__ Gtt,
    float* __restrict__ Vn, int Kdim)
{
  __shared__ unsigned short Ab[VN_E*258];   // fp16 eps*node rows, padded stride
  __shared__ unsigned short Bb[VN_E*258];   // fp16 V rows
  __shared__ unsigned short Xs[VN_E*32];    // per-slab X, swizzled 64B rows
  __shared__ unsigned short Gs[256*32];     // per-slab G, swizzled
  __shared__ int Ps[256];
  const int tid = threadIdx.x;
  const int e0 = blockIdx.x * VN_E;
  float ve = varepsp[0];
  float eps = rsqrtf(1.f + ve*ve);
  Ps[tid] = pairsG[tid];
  {
    int row = tid >> 3;            // 0..31
    int seg = (tid & 7) * 32;      // 0..224
    int s = senders[e0 + row];
    const float* ap = node + ((size_t)s << 8) + seg;
    const float* bp = V + (((size_t)(e0 + row)) << 8) + seg;
    unsigned short* ad = Ab + row*258 + seg;
    unsigned short* bd = Bb + row*258 + seg;
#pragma unroll
    for (int q = 0; q < 8; q++) {
      float4 fa = *(const float4*)(ap + q*4);
      float4 fb = *(const float4*)(bp + q*4);
      *(unsigned*)(ad + q*4)     = (unsigned)f2h(fa.x*eps) | ((unsigned)f2h(fa.y*eps) << 16);
      *(unsigned*)(ad + q*4 + 2) = (unsigned)f2h(fa.z*eps) | ((unsigned)f2h(fa.w*eps) << 16);
      *(unsigned*)(bd + q*4)     = (unsigned)f2h(fb.x) | ((unsigned)f2h(fb.y) << 16);
      *(unsigned*)(bd + q*4 + 2) = (unsigned)f2h(fb.z) | ((unsigned)f2h(fb.w) << 16);
    }
  }
  __syncthreads();
  const int wave = tid >> 6, lane = tid & 63;
  const int wr = (wave >> 1) * 16;       // row group: 0 or 16
  const int wc = (wave & 1) * 128;       // col group: 0 or 128
  const int fr = lane & 15, fk = (lane >> 4) * 8;
  const int xrow = tid >> 3;             // 0..31
  const int xkb  = (tid & 7) * 4;        // 0..28
  f32x4 acc[8] = {};
  const int nslab = Kdim >> 5;
  for (int sl = 0; sl < nslab; sl++) {
    // stage G slab (tiled layout: coalesced 64B per thread)
    {
      const unsigned short* gp = Gtt + ((size_t)(sl*256 + tid)) * 32;
#pragma unroll
      for (int q = 0; q < 4; q++) {
        uint4 v = *(const uint4*)(gp + q*8);
        *(uint4*)((char*)Gs + swz(tid, q*8)) = v;
      }
    }
    // compute X slab (2 pairs x 16 m)
    {
      int p0 = Ps[2*sl], p1 = Ps[2*sl+1];
#pragma unroll
      for (int q = 0; q < 4; q++) {
        int kk = xkb + q;
        int m16 = (kk & 15) << 4;
        int p = (kk < 16) ? p0 : p1;
        float av = h2f(Ab[xrow*258 + m16 + (p & 255)]);
        float bv = h2f(Bb[xrow*258 + m16 + ((p >> 8) & 255)]);
        *(unsigned short*)((char*)Xs + swz(xrow, kk)) = f2h(av*bv);
      }
    }
    __syncthreads();
    half8 af = *(half8*)((char*)Xs + swz(wr + fr, fk));
#pragma unroll
    for (int j = 0; j < 8; j++) {
      half8 bfj = *(half8*)((char*)Gs + swz(wc + j*16 + fr, fk));
      acc[j] = __builtin_amdgcn_mfma_f32_16x16x32_f16(af, bfj, acc[j], 0, 0, 0);
    }
    __syncthreads();
  }
  const int r4 = (lane >> 4) << 2;
#pragma unroll
  for (int j = 0; j < 8; j++) {
#pragma unroll
    for (int r = 0; r < 4; r++) {
      int row = e0 + wr + r4 + r;
      int col = wc + j*16 + (lane & 15);
      Vn[(size_t)row*256 + col] = acc[j][r];
    }
  }
}

// ---- Gtt[slab][col][32] = combined coupling x Wv matrix (fp16, tiled) ----
__global__ void gbuild_k(const float* __restrict__ TD,
    const float* __restrict__ Wv1, const float* __restrict__ Wv2,
    const float* __restrict__ Wv3, const int* __restrict__ sl_origc,
    unsigned short* __restrict__ Gt, int Kdim, int npairs,
    int s1b, int s1e, int s2e, int s3e)
{
  int k = blockIdx.x*256 + threadIdx.x;
  if (k >= Kdim) return;
  int col = blockIdx.y;
  int pair = k >> 4, m = k & 15;
  int d = col >> 4, kabs = col & 15;
  float acc = 0.f;
  if (kabs > 0 && pair < npairs) {
    const float* Wv; int ss, se, kloc;
    if (kabs < 4)      { Wv = Wv1; ss = s1b; se = s1e; kloc = kabs - 1; }
    else if (kabs < 9) { Wv = Wv2; ss = s1e; se = s2e; kloc = kabs - 4; }
    else               { Wv = Wv3; ss = s2e; se = s3e; kloc = kabs - 9; }
    for (int slot = ss; slot < se; slot++)
      acc += TD[((pair*30) + (slot - 4))*8 + kloc] * Wv[(sl_origc[slot] + m)*16 + d];
    acc *= rsqrtf((float)(16*(se - ss)));
  }
  Gt[((size_t)((k >> 5)*256 + col))*32 + (k & 31)] = f2h(acc);
}

// ---- weight convert + transpose: Wt[n][k] = fp16(W[k][n]) ----
struct WDesc { const float* src; unsigned short* dst; int K; int lgN; };
struct WPack { WDesc d[9]; };
__global__ void wcvt_k(WPack p){
  WDesc d = p.d[blockIdx.y];
  int total = d.K << d.lgN;
  int gid = blockIdx.x*256 + threadIdx.x;
  if (gid >= total) return;
  int k = gid >> d.lgN, n = gid & ((1 << d.lgN) - 1);
  d.dst[(size_t)n*d.K + k] = f2h(d.src[gid]);
}

// Generic fp32 tiled GEMM (small two-body layers).
template<int FLAGS>
__global__ __launch_bounds__(256) void gemm_k(
    const float* __restrict__ A1, const float* __restrict__ A2,
    int K1, int K, const float* __restrict__ W, int N,
    float* Cout,
    const float* __restrict__ env, const float* __restrict__ alphap,
    const float* Xres)
{
  __shared__ float As[16][68];
  __shared__ float Ws[16][68];
  const int tid = threadIdx.x;
  const int bm = blockIdx.x * 64;
  const int bn = blockIdx.y * 64;
  const int tx = tid & 15, ty = tid >> 4;
  const int K2 = K - K1;
  float acc[4][4] = {};
  for (int k0 = 0; k0 < K; k0 += 16) {
#pragma unroll
    for (int i = 0; i < 4; i++) {
      int idx = tid + i*256;
      int m = idx >> 4, kk = idx & 15;
      int k = k0 + kk;
      float v = 0.f;
      if (k < K) {
        int row = bm + m;
        v = (k < K1) ? A1[(size_t)row*K1 + k] : A2[(size_t)row*K2 + (k-K1)];
      }
      As[kk][m] = v;
    }
#pragma unroll
    for (int i = 0; i < 4; i++) {
      int idx = tid + i*256;
      int n = idx & 63, kk = idx >> 6;
      int k = k0 + kk, col = bn + n;
      Ws[kk][n] = (k < K && col < N) ? W[(size_t)k*N + col] : 0.f;
    }
    __syncthreads();
#pragma unroll
    for (int kk = 0; kk < 16; kk++) {
      float a[4], b[4];
#pragma unroll
      for (int i=0;i<4;i++) a[i] = As[kk][ty*4+i];
#pragma unroll
      for (int j=0;j<4;j++) b[j] = Ws[kk][tx*4+j];
#pragma unroll
      for (int i=0;i<4;i++)
#pragma unroll
        for (int j=0;j<4;j++)
          acc[i][j] += a[i]*b[j];
    }
    __syncthreads();
  }
  const float rscale = 1.f/sqrtf((float)K);
  float a2 = 0.f, inv1a2 = 1.f;
  if (FLAGS & F_RESID) { float al = alphap[0]; a2 = al*al; inv1a2 = 1.f/(1.f+a2); }
#pragma unroll
  for (int i=0;i<4;i++) {
    int row = bm + ty*4 + i;
    float ev = (FLAGS & F_ENV) ? env[row] : 1.f;
#pragma unroll
    for (int j=0;j<4;j++) {
      int col = bn + tx*4 + j;
      if (col >= N) continue;
      float v = acc[i][j]*rscale;
      if (FLAGS & F_SILU) v = v/(1.f+__expf(-v));
      if (FLAGS & F_ENV)  v *= ev;
      if (FLAGS & F_RESID) v = (Xres[(size_t)row*N+col] + a2*v)*inv1a2;
      Cout[(size_t)row*N+col] = v;
    }
  }
}

// dense to 16 outputs, K=256 fixed, scale 1/16
__global__ __launch_bounds__(256) void dense16_k(const float* __restrict__ A,
    const float* __restrict__ W, float* __restrict__ C)
{
  __shared__ float As[16*256];
  const int r0 = blockIdx.x << 4;
  const int tid = threadIdx.x;
  for (int i = tid; i < 16*256; i += 256)
    As[i] = A[((size_t)r0<<8) + i];
  __syncthreads();
  const int r = tid >> 4, n = tid & 15;
  float acc = 0.f;
#pragma unroll 8
  for (int k = 0; k < 256; k++)
    acc += As[(r<<8)+k] * W[(k<<4)+n];
  C[((size_t)(r0+r)<<4)+n] = acc * 0.0625f;
}

__global__ void edge_init_k(const float* __restrict__ vectors, const int* __restrict__ senders,
    const int* __restrict__ receivers, const int* __restrict__ species,
    const float* __restrict__ emb, float* __restrict__ envb, float* __restrict__ Yb,
    float* __restrict__ x72)
{
  const int e = blockIdx.x*256 + threadIdx.x;
  float vx = vectors[e*3+0], vy = vectors[e*3+1], vz = vectors[e*3+2];
  float d = sqrtf(vx*vx+vy*vy+vz*vz);
  float dd = (d==0.f) ? 1.f : d;
  float invd = 1.f/dd;
  float x = vx*invd, y = vy*invd, z = vz*invd;
  float d2=d*d, d3=d2*d, d6=d3*d3, d7=d6*d, d8=d7*d;
  float envv = (d<1.f) ? (1.f - 28.f*d6 + 48.f*d7 - 21.f*d8) : 0.f;
  envb[e] = envv;
  float mask = (d==0.f)?0.f:1.f;
  const float SQ2 = 1.41421356237309515f;
  const float PIf = 3.14159265358979323846f;
  float* xr = x72 + (size_t)e*72;
#pragma unroll
  for (int n=1;n<=8;n++)
    xr[n-1] = SQ2 * sinf((float)n*PIf*dd)*invd*envv*mask;
  int sp_s = species[senders[e]], sp_r = species[receivers[e]];
  const float* es_ = emb + (size_t)sp_s*32;
  const float* er_ = emb + (size_t)sp_r*32;
#pragma unroll 8
  for (int k=0;k<32;k++){ xr[8+k] = es_[k]*mask; xr[40+k] = er_[k]*mask; }
  float x2=x*x, y2=y*y, z2=z*z;
  const float s3=1.7320508075688772f, s15=3.872983346207417f, s5=2.23606797749979f;
  const float s358=2.0916500663351889f, s105=10.246950765959598f;
  const float s218=1.6201851746019651f, s7=2.6457513110645907f;
  float* Yr = Yb + ((size_t)e<<4);
  Yr[0]=1.f;           Yr[1]=s3*y;          Yr[2]=s3*z;           Yr[3]=s3*x;
  Yr[4]=s15*x*y;       Yr[5]=s15*y*z;       Yr[6]=0.5f*s5*(3.f*z2-1.f);
  Yr[7]=s15*x*z;       Yr[8]=0.5f*s15*(x2-y2);
  Yr[9]=s358*y*(3.f*x2-y2);  Yr[10]=s105*x*y*z;  Yr[11]=s218*y*(5.f*z2-1.f);
  Yr[12]=0.5f*s7*(5.f*z2-3.f)*z;  Yr[13]=s218*x*(5.f*z2-1.f);
  Yr[14]=0.5f*s105*(x2-y2)*z;     Yr[15]=s358*x*(x2-y2);
}

// V[e,m,k] = w0[e,m]*Y[e,k]
__global__ void vinit_k(const float* __restrict__ w0, const float* __restrict__ Y,
                        float* __restrict__ V)
{
  const int gid = blockIdx.x*256 + threadIdx.x;
  const int e = gid >> 8, idx = gid & 255;
  V[gid] = w0[(e<<4)+(idx>>4)] * Y[(e<<4)+(idx&15)];
}

// node[senders[e], m, k] += w[e,m]*Y[e,k]
__global__ void scatter_k(const float* __restrict__ w, const float* __restrict__ Y,
                          const int* __restrict__ senders, float* node)
{
  const int gid = blockIdx.x*256 + threadIdx.x;
  const int e = gid >> 8, idx = gid & 255;
  float v = w[(e<<4) + (idx>>4)] * Y[(e<<4) + (idx&15)];
  atomicAdd(&node[((size_t)senders[e]<<8) + idx], v);
}

// l3=0 TP (slots 0..3), one thread per (e, p*16+m). B = V (layer1) or Vn (layer2).
__global__ void tp2_k(const float* __restrict__ node, const float* __restrict__ Vn,
    const int* __restrict__ senders, const float* __restrict__ varepsp,
    const int* __restrict__ pmeta, const int* __restrict__ entIJ,
    const float* __restrict__ entVal, float* __restrict__ tp0)
{
  const int gid = blockIdx.x*256 + threadIdx.x;
  const int e = gid >> 6, c = gid & 63;
  const int p = c >> 4, m = c & 15;
  float ve = varepsp[0];
  float eps = rsqrtf(1.f + ve*ve);
  int s = senders[e];
  const float* Am = &node[((size_t)s<<8) + (m<<4)];
  const float* Bm = &Vn[((size_t)e<<8) + (m<<4)];
  int es = pmeta[p*4+1], ec = pmeta[p*4+2];
  float acc = 0.f;
  for (int t=0;t<ec;t++){
    int ij = entIJ[es+t];
    acc += entVal[es+t] * Am[ij&255] * Bm[(ij>>8)&255];
  }
  tp0[((size_t)e<<6) + pmeta[p*4+0] + m] = acc * eps;
}

// out[e] = env[e] * dot(X[e,:128], Wout) / sqrt(128)
__global__ void final_k(const float* __restrict__ X, const float* __restrict__ Wout,
                        const float* __restrict__ env, float* __restrict__ out)
{
  const int e = blockIdx.x*256 + threadIdx.x;
  float acc = 0.f;
#pragma unroll 16
  for (int k=0;k<128;k++) acc += X[((size_t)e<<7)+k]*Wout[k];
  out[e] = env[e]*acc*0.088388347648318447f;
}

// ============================ host launcher ============================

static void launch_gemm(int flags, const float* A1, const float* A2, int K1, int K,
    const float* W, int N, float* C, const float* env, const float* alphap,
    const float* Xres, hipStream_t stream)
{
  dim3 grid(E_EDGES/64, (N+63)/64);
  switch(flags){
    case F_NONE:        gemm_k<F_NONE>       <<<grid,256,0,stream>>>(A1,A2,K1,K,W,N,C,env,alphap,Xres); break;
    case F_SILU:        gemm_k<F_SILU>       <<<grid,256,0,stream>>>(A1,A2,K1,K,W,N,C,env,alphap,Xres); break;
    case F_ENV:         gemm_k<F_ENV>        <<<grid,256,0,stream>>>(A1,A2,K1,K,W,N,C,env,alphap,Xres); break;
    case F_ENV|F_RESID: gemm_k<F_ENV|F_RESID><<<grid,256,0,stream>>>(A1,A2,K1,K,W,N,C,env,alphap,Xres); break;
  }
}

static void launch_mgemm(int flags, const float* A1, const float* A2, int K1, int K,
    const unsigned short* Wt, int N, float* C, const float* env, const float* alphap,
    const float* Xres, hipStream_t stream)
{
  dim3 grid(E_EDGES/128, N/128);
  switch(flags){
    case F_NONE:        mgemm_k<F_NONE>       <<<grid,256,0,stream>>>(A1,A2,K1,K,Wt,N,C,env,alphap,Xres); break;
    case F_SILU:        mgemm_k<F_SILU>       <<<grid,256,0,stream>>>(A1,A2,K1,K,Wt,N,C,env,alphap,Xres); break;
    case F_ENV:         mgemm_k<F_ENV>        <<<grid,256,0,stream>>>(A1,A2,K1,K,Wt,N,C,env,alphap,Xres); break;
    case F_ENV|F_RESID: mgemm_k<F_ENV|F_RESID><<<grid,256,0,stream>>>(A1,A2,K1,K,Wt,N,C,env,alphap,Xres); break;
  }
}

extern "C" void kernel_launch(void* const* d_in, const int* in_sizes, int n_in,
                              void* d_out, int out_size, void* d_ws, size_t ws_size,
                              hipStream_t stream)
{
  const float* vectors = (const float*)d_in[0];
  const float* vareps  = (const float*)d_in[1];
  const float* alpha   = (const float*)d_in[2];
  const float* emb     = (const float*)d_in[3];
  const float* W_tb1   = (const float*)d_in[4];
  const float* W_tb2   = (const float*)d_in[5];
  const float* W_tb3   = (const float*)d_in[6];
  const float* W_tb4   = (const float*)d_in[7];
  const float* W_w0    = (const float*)d_in[8];
  const float* W_w1    = (const float*)d_in[9];
  const float* W_l11   = (const float*)d_in[10];
  const float* W_l12   = (const float*)d_in[11];
  const float* W_l13   = (const float*)d_in[12];
  const float* W_v1    = (const float*)d_in[13];
  const float* W_v2    = (const float*)d_in[14];
  const float* W_v3    = (const float*)d_in[15];
  const float* W_w2    = (const float*)d_in[16];
  const float* W_l21   = (const float*)d_in[17];
  const float* W_l22   = (const float*)d_in[18];
  const float* W_l23   = (const float*)d_in[19];
  const float* W_h     = (const float*)d_in[20];
  const float* W_out   = (const float*)d_in[21];
  const int* senders   = (const int*)d_in[22];
  const int* receivers = (const int*)d_in[23];
  const int* species   = (const int*)d_in[24];

  static cgt::Tables tb;
  cgt::build(tb);
  const int Kdim = tb.npairs * 16;

  char* ws = (char*)d_ws;
  size_t off = 0;
  auto alloc = [&](size_t bytes)->void*{
    void* p = ws + off; off += (bytes + 255) & ~(size_t)255; return p;
  };
  float* t_val = (float*)alloc(sizeof(tb.val));
  int*   t_ij  = (int*)  alloc(sizeof(tb.ij));
  int*   t_pm  = (int*)  alloc(sizeof(tb.pmeta));
  float* t_td  = (float*)alloc(sizeof(tb.TD));
  int*   t_pr  = (int*)  alloc(sizeof(tb.pairs));
  int*   t_oc  = (int*)  alloc(sizeof(tb.sl_origc));
  float* envb  = (float*)alloc((size_t)E_EDGES*4);
  float* Yb    = (float*)alloc((size_t)E_EDGES*16*4);
  float* xb    = (float*)alloc((size_t)E_EDGES*256*4);
  float* Vb    = (float*)alloc((size_t)E_EDGES*256*4);   // V, then Vn (in-place)
  float* bufA  = (float*)alloc((size_t)E_EDGES*256*4);
  float* bufB  = (float*)alloc((size_t)E_EDGES*256*4);
  float* wb    = (float*)alloc((size_t)E_EDGES*16*4);
  float* tp0b  = (float*)alloc((size_t)E_EDGES*64*4);
  float* nodeb = (float*)alloc((size_t)NNODES*256*4);
  unsigned short* Gt = (unsigned short*)alloc((size_t)256*Kdim*2);
  unsigned short* Wt_tb3 = (unsigned short*)alloc(64*128*2);
  unsigned short* Wt_tb4 = (unsigned short*)alloc(128*256*2);
  unsigned short* Wt_l11 = (unsigned short*)alloc(320*256*2);
  unsigned short* Wt_l12 = (unsigned short*)alloc(256*256*2);
  unsigned short* Wt_l13 = (unsigned short*)alloc(256*256*2);
  unsigned short* Wt_l21 = (unsigned short*)alloc(320*256*2);
  unsigned short* Wt_l22 = (unsigned short*)alloc(256*256*2);
  unsigned short* Wt_l23 = (unsigned short*)alloc(256*256*2);
  unsigned short* Wt_h   = (unsigned short*)alloc(256*128*2);
  if (off > ws_size) {
    fprintf(stderr, "[allegro] workspace too small: need %zu, have %zu\n", off, ws_size);
    return;
  }

  hipMemcpyAsync(t_val, tb.val,     sizeof(tb.val),     hipMemcpyHostToDevice, stream);
  hipMemcpyAsync(t_ij,  tb.ij,      sizeof(tb.ij),      hipMemcpyHostToDevice, stream);
  hipMemcpyAsync(t_pm,  tb.pmeta,   sizeof(tb.pmeta),   hipMemcpyHostToDevice, stream);
  hipMemcpyAsync(t_td,  tb.TD,      sizeof(tb.TD),      hipMemcpyHostToDevice, stream);
  hipMemcpyAsync(t_pr,  tb.pairs,   sizeof(tb.pairs),   hipMemcpyHostToDevice, stream);
  hipMemcpyAsync(t_oc,  tb.sl_origc,sizeof(tb.sl_origc),hipMemcpyHostToDevice, stream);

  // slot ranges (l3 blocks contiguous in slot order): l1: [s1b,s1e) etc.
  const int s1b = tb.l3np[0];
  const int s1e = s1b + tb.l3np[1];
  const int s2e = s1e + tb.l3np[2];
  const int s3e = s2e + tb.l3np[3];

  // combined coupling x Wv matrix (fp16, tiled [slab][col][32])
  {
    dim3 g((Kdim + 255)/256, 256);
    gbuild_k<<<g, 256, 0, stream>>>(t_td, W_v1, W_v2, W_v3, t_oc, Gt, Kdim,
                                    tb.npairs, s1b, s1e, s2e, s3e);
  }
  // weight convert+transpose (fp16)
  {
    WPack p;
    p.d[0] = { W_tb3, Wt_tb3,  64, 7 };
    p.d[1] = { W_tb4, Wt_tb4, 128, 8 };
    p.d[2] = { W_l11, Wt_l11, 320, 8 };
    p.d[3] = { W_l12, Wt_l12, 256, 8 };
    p.d[4] = { W_l13, Wt_l13, 256, 8 };
    p.d[5] = { W_l21, Wt_l21, 320, 8 };
    p.d[6] = { W_l22, Wt_l22, 256, 8 };
    p.d[7] = { W_h,   Wt_h,   256, 7 };
    p.d[8] = { W_l23, Wt_l23, 256, 8 };
    dim3 g(320, 9);
    wcvt_k<<<g, 256, 0, stream>>>(p);
  }

  // 1. edge features + Y + env
  edge_init_k<<<E_EDGES/256, 256, 0, stream>>>(vectors, senders, receivers, species,
                                               emb, envb, Yb, bufA);
  // 2. two-body MLP: 72 -> 32 -> 64 (fp32) -> 128 -> 256 (fp16 MFMA)
  launch_gemm (F_SILU, bufA, nullptr, 72, 72,  W_tb1, 32,   bufB, envb, alpha, nullptr, stream);
  launch_gemm (F_SILU, bufB, nullptr, 32, 32,  W_tb2, 64,   bufA, envb, alpha, nullptr, stream);
  launch_mgemm(F_SILU, bufA, nullptr, 64, 64,  Wt_tb3, 128, bufB, envb, alpha, nullptr, stream);
  launch_mgemm(F_ENV,  bufB, nullptr, 128,128, Wt_tb4, 256, xb,   envb, alpha, nullptr, stream);
  // 3. V = dense(x,W_w0) outer Y
  dense16_k<<<E_EDGES/16, 256, 0, stream>>>(xb, W_w0, wb);
  vinit_k<<<E_EDGES, 256, 0, stream>>>(wb, Yb, Vb);

  // ---- layer 1 ----
  dense16_k<<<E_EDGES/16, 256, 0, stream>>>(xb, W_w1, wb);
  hipMemsetAsync(nodeb, 0, (size_t)NNODES*256*4, stream);
  scatter_k<<<E_EDGES, 256, 0, stream>>>(wb, Yb, senders, nodeb);
  // tp0 (l3=0) exact fp32; B = V
  tp2_k<<<E_EDGES*64/256, 256, 0, stream>>>(nodeb, Vb, senders, vareps, t_pm, t_ij,
                                            t_val, tp0b);
  // Vn: fused on-the-fly X + fp16 MFMA (in-place V -> Vn)
  vn_k<<<E_EDGES/VN_E, 256, 0, stream>>>(nodeb, Vb, senders, vareps, t_pr, Gt, Vb, Kdim);
  launch_mgemm(F_SILU,        xb,   tp0b,   256, 320, Wt_l11, 256, bufB, envb, alpha, nullptr, stream);
  launch_mgemm(F_SILU,        bufB, nullptr,256, 256, Wt_l12, 256, bufA, envb, alpha, nullptr, stream);
  launch_mgemm(F_ENV|F_RESID, bufA, nullptr,256, 256, Wt_l13, 256, xb,   envb, alpha, xb,      stream);

  // ---- layer 2 (lmax_out = 0) ----
  dense16_k<<<E_EDGES/16, 256, 0, stream>>>(xb, W_w2, wb);
  hipMemsetAsync(nodeb, 0, (size_t)NNODES*256*4, stream);
  scatter_k<<<E_EDGES, 256, 0, stream>>>(wb, Yb, senders, nodeb);
  tp2_k<<<E_EDGES*64/256, 256, 0, stream>>>(nodeb, Vb, senders, vareps, t_pm, t_ij,
                                            t_val, tp0b);
  launch_mgemm(F_SILU,        xb,   tp0b,   256, 320, Wt_l21, 256, bufB, envb, alpha, nullptr, stream);
  launch_mgemm(F_SILU,        bufB, nullptr,256, 256, Wt_l22, 256, bufA, envb, alpha, nullptr, stream);
  launch_mgemm(F_ENV|F_RESID, bufA, nullptr,256, 256, Wt_l23, 256, xb,   envb, alpha, xb,      stream);

  // ---- head ----
  launch_mgemm(F_NONE, xb, nullptr, 256, 256, Wt_h, 128, bufB, envb, alpha, nullptr, stream);
  final_k<<<E_EDGES/256, 256, 0, stream>>>(bufB, W_out, envb, (float*)d_out);
}

// Round 7
// 647.883 us; speedup vs baseline: 1.6012x; 1.0895x over previous
//
#include <hip/hip_runtime.h>
#include <cmath>
#include <complex>
#include <cstdio>
#include <cstring>
#include <algorithm>

#define E_EDGES 32768
#define NNODES  2048
#define VN_E    32      // edges per vn_k block

// ============================ host-side CG tables ============================
namespace cgt {

static double fct(int n){
  static const double f[13] = {1.,1.,2.,6.,24.,120.,720.,5040.,40320.,362880.,
                               3628800.,39916800.,479001600.};
  return f[n];
}

static double cg(int j1,int m1,int j2,int m2,int j3,int m3){
  if (m1+m2 != m3) return 0.0;
  double pre = std::sqrt((2*j3+1)*fct(j1+j2-j3)*fct(j1-j2+j3)*fct(-j1+j2+j3)/fct(j1+j2+j3+1));
  pre *= std::sqrt(fct(j3+m3)*fct(j3-m3)*fct(j1-m1)*fct(j1+m1)*fct(j2-m2)*fct(j2+m2));
  int kmin = 0;
  if (j2-j3-m1 > kmin) kmin = j2-j3-m1;
  if (j1-j3+m2 > kmin) kmin = j1-j3+m2;
  int kmax = j1+j2-j3;
  if (j1-m1 < kmax) kmax = j1-m1;
  if (j2+m2 < kmax) kmax = j2+m2;
  double s = 0.0;
  for (int k=kmin;k<=kmax;k++){
    double d = fct(k)*fct(j1+j2-j3-k)*fct(j1-m1-k)*fct(j2+m2-k)*fct(j3-j2+m1+k)*fct(j3-j1-m2+k);
    s += ((k&1)? -1.0:1.0)/d;
  }
  return pre*s;
}

typedef std::complex<double> cd;

static void umat(int l, cd U[7][7]){
  for (int a=0;a<7;a++) for (int b=0;b<7;b++) U[a][b]=cd(0,0);
  U[l][l] = cd(1,0);
  double s2 = 1.0/std::sqrt(2.0);
  for (int m=1;m<=l;m++){
    double sg = (m&1)? -1.0 : 1.0;
    U[l+m][l-m] = cd(s2,0);
    U[l+m][l+m] = cd(sg*s2,0);
    U[l-m][l-m] = cd(0, s2);
    U[l-m][l+m] = cd(0, -sg*s2);
  }
}

static bool realCoupling(int l1,int l2,int l3, double T[7][7][7]){
  cd U1[7][7],U2[7][7],U3[7][7];
  umat(l1,U1); umat(l2,U2); umat(l3,U3);
  int n1=2*l1+1, n2=2*l2+1, n3=2*l3+1;
  double Cg[7][7][7];
  for (int m=0;m<n1;m++) for(int n=0;n<n2;n++) for(int k=0;k<n3;k++)
    Cg[m][n][k] = cg(l1,m-l1,l2,n-l2,l3,k-l3);
  double Tr[7][7][7], Ti[7][7][7];
  double nr=0, ni=0;
  for (int a=0;a<n1;a++) for(int b=0;b<n2;b++) for(int c=0;c<n3;c++){
    cd s(0,0);
    for (int m=0;m<n1;m++){
      if (U1[a][m]==cd(0,0)) continue;
      for (int n=0;n<n2;n++){
        if (U2[b][n]==cd(0,0)) continue;
        for (int k=0;k<n3;k++){
          double cgv = Cg[m][n][k];
          if (cgv==0.0) continue;
          s += U1[a][m]*U2[b][n]*std::conj(U3[c][k])*cgv;
        }
      }
    }
    Tr[a][b][c]=s.real(); Ti[a][b][c]=s.imag();
    nr += s.real()*s.real(); ni += s.imag()*s.imag();
  }
  bool useR = (nr >= ni);
  double nn = std::sqrt(useR? nr : ni);
  if (nn < 1e-8) return false;
  for (int a=0;a<n1;a++)for(int b=0;b<n2;b++)for(int c=0;c<n3;c++)
    T[a][b][c] = (useR? Tr[a][b][c] : Ti[a][b][c])/nn;
  return true;
}

struct Tables {
  float val[4096];
  int   ij[4096];        // (a_abs) | (b_abs<<8), entries grouped by (path, c)
  int   pmeta[40*4];     // per SLOT: tpOff(orig layout), entStart, entCount, kdim
  int   ccnt[40*8];      // per SLOT: entry count for each c (kd <= 7)
  int   l3base[4];
  int   l3np[4];
  int   npaths;
  int   nent;
  int   tptot;
  // --- pair/TD tables for the fused Vn GEMM (l>=1 slots only) ---
  int   pairs[256];      // raw (a_abs) | (b_abs<<8)
  float TD[256*30*8];    // TD[pair][slot-4][kloc] = T*sqrt(2l3+1)
  int   sl_origc[40];    // per slot: original c-base (origIdxInL*16) for Wv rows
  int   npairs;          // padded even
};

struct PathTmp {
  int l1,l2,l3, tpoff, kd;
  int ec;                 // total nonzero entries
  double T[7][7][7];
};

static void build(Tables& tb){
  static PathTmp paths[40];
  int np = 0, tpoff = 0;
  int l3start[5];
  for (int l3=0;l3<=3;l3++){
    tb.l3base[l3] = tpoff;
    l3start[l3] = np;
    int kd = 2*l3+1;
    for (int l1=0;l1<=3;l1++) for (int l2=0;l2<=3;l2++){
      int lo = (l1>l2)? l1-l2 : l2-l1;
      int hi = std::min(l1+l2,3);
      if (l3 < lo || l3 > hi) continue;
      PathTmp& pt = paths[np];
      if (!realCoupling(l1,l2,l3,pt.T)) continue;
      pt.l1=l1; pt.l2=l2; pt.l3=l3; pt.kd=kd; pt.tpoff=tpoff;
      double scale = std::sqrt((double)kd);
      int cnt = 0;
      for (int a=0;a<2*l1+1;a++)for(int b=0;b<2*l2+1;b++)for(int c=0;c<kd;c++)
        if (std::fabs(pt.T[a][b][c]*scale) > 1e-7) cnt++;
      pt.ec = cnt;
      tpoff += 16*kd;
      np++;
    }
  }
  l3start[4] = np;
  for (int l3=0;l3<=3;l3++) tb.l3np[l3] = l3start[l3+1]-l3start[l3];
  static int order[40];
  for (int i=0;i<np;i++) order[i]=i;
  for (int l3=0;l3<=3;l3++)
    std::sort(order+l3start[l3], order+l3start[l3+1],
              [&](int a,int b){ return paths[a].ec > paths[b].ec; });
  // emit entries grouped by (slot, c); build pair map + TD for l>=1 slots
  std::memset(tb.TD, 0, sizeof(tb.TD));
  std::memset(tb.pairs, 0, sizeof(tb.pairs));
  static int pmap[16][16];
  for (int i=0;i<16;i++) for (int j=0;j<16;j++) pmap[i][j] = -1;
  int npr = 0;
  int ep = 0;
  for (int slot=0; slot<np; slot++){
    const PathTmp& pt = paths[order[slot]];
    double scale = std::sqrt((double)pt.kd);
    int s1 = pt.l1*pt.l1, s2 = pt.l2*pt.l2;
    tb.pmeta[slot*4+0] = pt.tpoff;
    tb.pmeta[slot*4+1] = ep;
    tb.sl_origc[slot] = ((pt.tpoff - tb.l3base[pt.l3]) / (16*pt.kd)) * 16;
    int tot = 0;
    for (int c=0;c<pt.kd;c++){
      int cnt = 0;
      for (int a=0;a<2*pt.l1+1;a++)for(int b=0;b<2*pt.l2+1;b++){
        double v = pt.T[a][b][c]*scale;
        if (std::fabs(v) > 1e-7){
          tb.val[ep] = (float)v;
          tb.ij[ep]  = (s1+a) | ((s2+b)<<8);
          ep++; cnt++;
          if (pt.l3 >= 1){
            int aa = s1+a, bb = s2+b;
            int pi = pmap[aa][bb];
            if (pi < 0){ pi = npr; pmap[aa][bb] = pi;
                         tb.pairs[npr] = aa | (bb<<8); npr++; }
            tb.TD[(pi*30 + (slot-4))*8 + c] = (float)v;
          }
        }
      }
      tb.ccnt[slot*8+c] = cnt;
      tot += cnt;
    }
    for (int c=pt.kd;c<8;c++) tb.ccnt[slot*8+c]=0;
    tb.pmeta[slot*4+2] = tot;
    tb.pmeta[slot*4+3] = pt.kd;
  }
  if (npr & 1){ tb.pairs[npr] = 0; npr++; }   // pad to even -> Kdim % 32 == 0
  tb.npairs = npr;
  tb.npaths = np; tb.nent = ep; tb.tptot = tpoff;
}

} // namespace cgt

// ============================ device kernels ============================
// LAYOUT CONVENTION (R7): node/V/Vn rows are [a][m] (spherical-major,
// element (m,a) at a*16+m). Fixes vn_k X-compute stride-16 LDS conflicts
// (4.9e7 in R6) and makes tp2_k reads coalesced across m-lanes.

enum GFlags { F_NONE=0, F_SILU=1, F_ENV=2, F_RESID=4 };

typedef _Float16 half8 __attribute__((ext_vector_type(8)));
typedef _Float16 half4 __attribute__((ext_vector_type(4)));
typedef __attribute__((ext_vector_type(4))) float f32x4;

__device__ inline unsigned short f2h(float f){
  union { _Float16 h; unsigned short u; } x;
  x.h = (_Float16)f;           // v_cvt_f16_f32, RNE
  return x.u;
}
__device__ inline float h2f(unsigned short u){
  union { _Float16 h; unsigned short u; } x; x.u = u;
  return (float)x.h;
}

// XOR swizzle for 64B-row LDS tiles of 16-bit data: permutes 16B units so
// ds_read_b128 fragment loads are ~conflict-free. kh in ushort units (mult of 4).
__device__ inline int swz(int row, int kh){
  int b = row*64 + kh*2;
  return b ^ (((row >> 1) & 3) << 4);
}

// ---- fp16 MFMA GEMM: C[M,N] = post( A[M,K] @ W[K,N] / sqrt(K) ), A fp32 ----
template<int FLAGS>
__global__ __launch_bounds__(256) void mgemm_k(
    const float* __restrict__ A1, const float* __restrict__ A2,
    int K1, int K, const unsigned short* __restrict__ Wt, int N,
    float* Cout, const float* __restrict__ env,
    const float* __restrict__ alphap, const float* Xres)
{
  __shared__ unsigned short AsB[128*32];
  __shared__ unsigned short BsB[128*32];
  const int tid  = threadIdx.x;
  const int wave = tid >> 6, lane = tid & 63;
  const int bm = blockIdx.x*128, bn = blockIdx.y*128;
  const int wr = (wave >> 1)*64, wc = (wave & 1)*64;
  const int K2 = K - K1;
  f32x4 acc[4][4] = {};

  const int sr  = tid >> 3;          // staging row 0..31 (A)
  const int skq = (tid & 7) * 4;     // staging k 0..28 step 4 (A)
  const int bn_ = tid >> 1;          // staging n 0..127 (B)
  const int bkh = (tid & 1) * 16;    // staging k half (B)

  for (int k0 = 0; k0 < K; k0 += 32) {
#pragma unroll
    for (int q = 0; q < 4; q++) {
      int row = q*32 + sr;
      int grow = bm + row;
      int kk = k0 + skq;
      float4 f4 = (kk < K1) ? *(const float4*)(A1 + (size_t)grow*K1 + kk)
                            : *(const float4*)(A2 + (size_t)grow*K2 + (kk - K1));
      ushort4 u;
      u.x = f2h(f4.x); u.y = f2h(f4.y); u.z = f2h(f4.z); u.w = f2h(f4.w);
      *(ushort4*)((char*)AsB + swz(row, skq)) = u;
    }
    {
      const unsigned short* s = Wt + (size_t)(bn + bn_)*K + k0 + bkh;
#pragma unroll
      for (int q = 0; q < 4; q++) {
        ushort4 u = *(const ushort4*)(s + q*4);
        *(ushort4*)((char*)BsB + swz(bn_, bkh + q*4)) = u;
      }
    }
    __syncthreads();
    const int fr = lane & 15, fk = (lane >> 4) * 8;
    half8 af[4], bf[4];
#pragma unroll
    for (int i = 0; i < 4; i++)
      af[i] = *(half8*)((char*)AsB + swz(wr + i*16 + fr, fk));
#pragma unroll
    for (int j = 0; j < 4; j++)
      bf[j] = *(half8*)((char*)BsB + swz(wc + j*16 + fr, fk));
#pragma unroll
    for (int i = 0; i < 4; i++)
#pragma unroll
      for (int j = 0; j < 4; j++)
        acc[i][j] = __builtin_amdgcn_mfma_f32_16x16x32_f16(af[i], bf[j], acc[i][j], 0, 0, 0);
    __syncthreads();
  }

  const float rscale = 1.f/sqrtf((float)K);
  float a2 = 0.f, inv1a2 = 1.f;
  if (FLAGS & F_RESID) { float al = alphap[0]; a2 = al*al; inv1a2 = 1.f/(1.f+a2); }
#pragma unroll
  for (int i = 0; i < 4; i++) {
#pragma unroll
    for (int r = 0; r < 4; r++) {
      int row = bm + wr + i*16 + ((lane >> 4) << 2) + r;
      float ev = (FLAGS & F_ENV) ? env[row] : 1.f;
#pragma unroll
      for (int j = 0; j < 4; j++) {
        int col = bn + wc + j*16 + (lane & 15);
        float v = acc[i][j][r]*rscale;
        if (FLAGS & F_SILU) v = v/(1.f+__expf(-v));
        if (FLAGS & F_ENV)  v *= ev;
        if (FLAGS & F_RESID) v = (Xres[(size_t)row*N+col] + a2*v)*inv1a2;
        Cout[(size_t)row*N+col] = v;
      }
    }
  }
}

// ---- fused Vn kernel: per 32 edges, compute X slab on the fly + MFMA ----
// Vn[e, kabs*16+d] = sum_k X[e,k] * G[k, col];  X[(pair,m)] = (eps*node[s])(m,a)*V[e](m,b)
// node/V in [a][m] layout: X compute = 2x ds_read_b64 + v_pk_mul_f16 + ds_write_b64.
__global__ __launch_bounds__(256) void vn_k(
    const float* __restrict__ node, const float* __restrict__ V,
    const int* __restrict__ senders, const float* __restrict__ varepsp,
    const int* __restrict__ pairsG, const unsigned short* __restrict__ Gtt,
    float* __restrict__ Vn, int Kdim)
{
  __shared__ unsigned short Ab[VN_E*264];   // fp16 eps*node rows, pad 264 (4-bank/row rot)
  __shared__ unsigned short Bb[VN_E*264];   // fp16 V rows
  __shared__ unsigned short Xs[VN_E*32];    // per-slab X, swizzled 64B rows
  __shared__ unsigned short Gs[256*32];     // per-slab G, swizzled
  __shared__ int Ps[256];
  const int tid = threadIdx.x;
  const int e0 = blockIdx.x * VN_E;
  float ve = varepsp[0];
  float eps = rsqrtf(1.f + ve*ve);
  Ps[tid] = pairsG[tid];
  {
    int row = tid >> 3;            // 0..31
    int seg = (tid & 7) * 32;      // 0..224
    int s = senders[e0 + row];
    const float* ap = node + ((size_t)s << 8) + seg;
    const float* bp = V + (((size_t)(e0 + row)) << 8) + seg;
    unsigned short* ad = Ab + row*264 + seg;
    unsigned short* bd = Bb + row*264 + seg;
#pragma unroll
    for (int q = 0; q < 8; q++) {
      float4 fa = *(const float4*)(ap + q*4);
      float4 fb = *(const float4*)(bp + q*4);
      *(unsigned*)(ad + q*4)     = (unsigned)f2h(fa.x*eps) | ((unsigned)f2h(fa.y*eps) << 16);
      *(unsigned*)(ad + q*4 + 2) = (unsigned)f2h(fa.z*eps) | ((unsigned)f2h(fa.w*eps) << 16);
      *(unsigned*)(bd + q*4)     = (unsigned)f2h(fb.x) | ((unsigned)f2h(fb.y) << 16);
      *(unsigned*)(bd + q*4 + 2) = (unsigned)f2h(fb.z) | ((unsigned)f2h(fb.w) << 16);
    }
  }
  __syncthreads();
  const int wave = tid >> 6, lane = tid & 63;
  const int wr = (wave >> 1) * 16;       // row group: 0 or 16
  const int wc = (wave & 1) * 128;       // col group: 0 or 128
  const int fr = lane & 15, fk = (lane >> 4) * 8;
  const int xrow = tid >> 3;             // 0..31
  const int xkb  = (tid & 7) * 4;        // 0..28
  const int xrb  = xrow * 264;
  f32x4 acc[8] = {};
  const int nslab = Kdim >> 5;
  for (int sl = 0; sl < nslab; sl++) {
    // issue G slab loads early (latency hides under X compute)
    const unsigned short* gp = Gtt + ((size_t)(sl*256 + tid)) * 32;
    uint4 g0 = *(const uint4*)gp;
    uint4 g1 = *(const uint4*)(gp + 8);
    uint4 g2 = *(const uint4*)(gp + 16);
    uint4 g3 = *(const uint4*)(gp + 24);
    // compute X slab: 4 consecutive m for one pair -> vector LDS ops
    {
      int p = Ps[2*sl + (xkb >> 4)];
      int mloc = xkb & 15;               // 0,4,8,12
      half4 av = *(const half4*)(Ab + xrb + ((p & 255) << 4) + mloc);
      half4 bv = *(const half4*)(Bb + xrb + (((p >> 8) & 255) << 4) + mloc);
      half4 xv = av * bv;
      *(half4*)((char*)Xs + swz(xrow, xkb)) = xv;
    }
    // write G slab to LDS
    *(uint4*)((char*)Gs + swz(tid, 0))  = g0;
    *(uint4*)((char*)Gs + swz(tid, 8))  = g1;
    *(uint4*)((char*)Gs + swz(tid, 16)) = g2;
    *(uint4*)((char*)Gs + swz(tid, 24)) = g3;
    __syncthreads();
    half8 af = *(half8*)((char*)Xs + swz(wr + fr, fk));
#pragma unroll
    for (int j = 0; j < 8; j++) {
      half8 bfj = *(half8*)((char*)Gs + swz(wc + j*16 + fr, fk));
      acc[j] = __builtin_amdgcn_mfma_f32_16x16x32_f16(af, bfj, acc[j], 0, 0, 0);
    }
    __syncthreads();
  }
  const int r4 = (lane >> 4) << 2;
#pragma unroll
  for (int j = 0; j < 8; j++) {
#pragma unroll
    for (int r = 0; r < 4; r++) {
      int row = e0 + wr + r4 + r;
      int col = wc + j*16 + (lane & 15);
      Vn[(size_t)row*256 + col] = acc[j][r];
    }
  }
}

// ---- Gtt[slab][col][32] = coupling x Wv (fp16, tiled). col = kabs*16+d ----
__global__ void gbuild_k(const float* __restrict__ TD,
    const float* __restrict__ Wv1, const float* __restrict__ Wv2,
    const float* __restrict__ Wv3, const int* __restrict__ sl_origc,
    unsigned short* __restrict__ Gt, int Kdim, int npairs,
    int s1b, int s1e, int s2e, int s3e)
{
  int k = blockIdx.x*256 + threadIdx.x;
  if (k >= Kdim) return;
  int col = blockIdx.y;
  int pair = k >> 4, m = k & 15;
  int d = col & 15, kabs = col >> 4;     // transposed output convention
  float acc = 0.f;
  if (kabs > 0 && pair < npairs) {
    const float* Wv; int ss, se, kloc;
    if (kabs < 4)      { Wv = Wv1; ss = s1b; se = s1e; kloc = kabs - 1; }
    else if (kabs < 9) { Wv = Wv2; ss = s1e; se = s2e; kloc = kabs - 4; }
    else               { Wv = Wv3; ss = s2e; se = s3e; kloc = kabs - 9; }
    for (int slot = ss; slot < se; slot++)
      acc += TD[((pair*30) + (slot - 4))*8 + kloc] * Wv[(sl_origc[slot] + m)*16 + d];
    acc *= rsqrtf((float)(16*(se - ss)));
  }
  Gt[((size_t)((k >> 5)*256 + col))*32 + (k & 31)] = f2h(acc);
}

// ---- weight convert + transpose: Wt[n][k] = fp16(W[k][n]) ----
struct WDesc { const float* src; unsigned short* dst; int K; int lgN; };
struct WPack { WDesc d[9]; };
__global__ void wcvt_k(WPack p){
  WDesc d = p.d[blockIdx.y];
  int total = d.K << d.lgN;
  int gid = blockIdx.x*256 + threadIdx.x;
  if (gid >= total) return;
  int k = gid >> d.lgN, n = gid & ((1 << d.lgN) - 1);
  d.dst[(size_t)n*d.K + k] = f2h(d.src[gid]);
}

// Generic fp32 tiled GEMM (small two-body layers).
template<int FLAGS>
__global__ __launch_bounds__(256) void gemm_k(
    const float* __restrict__ A1, const float* __restrict__ A2,
    int K1, int K, const float* __restrict__ W, int N,
    float* Cout,
    const float* __restrict__ env, const float* __restrict__ alphap,
    const float* Xres)
{
  __shared__ float As[16][68];
  __shared__ float Ws[16][68];
  const int tid = threadIdx.x;
  const int bm = blockIdx.x * 64;
  const int bn = blockIdx.y * 64;
  const int tx = tid & 15, ty = tid >> 4;
  const int K2 = K - K1;
  float acc[4][4] = {};
  for (int k0 = 0; k0 < K; k0 += 16) {
#pragma unroll
    for (int i = 0; i < 4; i++) {
      int idx = tid + i*256;
      int m = idx >> 4, kk = idx & 15;
      int k = k0 + kk;
      float v = 0.f;
      if (k < K) {
        int row = bm + m;
        v = (k < K1) ? A1[(size_t)row*K1 + k] : A2[(size_t)row*K2 + (k-K1)];
      }
      As[kk][m] = v;
    }
#pragma unroll
    for (int i = 0; i < 4; i++) {
      int idx = tid + i*256;
      int n = idx & 63, kk = idx >> 6;
      int k = k0 + kk, col = bn + n;
      Ws[kk][n] = (k < K && col < N) ? W[(size_t)k*N + col] : 0.f;
    }
    __syncthreads();
#pragma unroll
    for (int kk = 0; kk < 16; kk++) {
      float a[4], b[4];
#pragma unroll
      for (int i=0;i<4;i++) a[i] = As[kk][ty*4+i];
#pragma unroll
      for (int j=0;j<4;j++) b[j] = Ws[kk][tx*4+j];
#pragma unroll
      for (int i=0;i<4;i++)
#pragma unroll
        for (int j=0;j<4;j++)
          acc[i][j] += a[i]*b[j];
    }
    __syncthreads();
  }
  const float rscale = 1.f/sqrtf((float)K);
  float a2 = 0.f, inv1a2 = 1.f;
  if (FLAGS & F_RESID) { float al = alphap[0]; a2 = al*al; inv1a2 = 1.f/(1.f+a2); }
#pragma unroll
  for (int i=0;i<4;i++) {
    int row = bm + ty*4 + i;
    float ev = (FLAGS & F_ENV) ? env[row] : 1.f;
#pragma unroll
    for (int j=0;j<4;j++) {
      int col = bn + tx*4 + j;
      if (col >= N) continue;
      float v = acc[i][j]*rscale;
      if (FLAGS & F_SILU) v = v/(1.f+__expf(-v));
      if (FLAGS & F_ENV)  v *= ev;
      if (FLAGS & F_RESID) v = (Xres[(size_t)row*N+col] + a2*v)*inv1a2;
      Cout[(size_t)row*N+col] = v;
    }
  }
}

// dense to 16 outputs, K=256 fixed, scale 1/16
__global__ __launch_bounds__(256) void dense16_k(const float* __restrict__ A,
    const float* __restrict__ W, float* __restrict__ C)
{
  __shared__ float As[16*256];
  const int r0 = blockIdx.x << 4;
  const int tid = threadIdx.x;
  for (int i = tid; i < 16*256; i += 256)
    As[i] = A[((size_t)r0<<8) + i];
  __syncthreads();
  const int r = tid >> 4, n = tid & 15;
  float acc = 0.f;
#pragma unroll 8
  for (int k = 0; k < 256; k++)
    acc += As[(r<<8)+k] * W[(k<<4)+n];
  C[((size_t)(r0+r)<<4)+n] = acc * 0.0625f;
}

__global__ void edge_init_k(const float* __restrict__ vectors, const int* __restrict__ senders,
    const int* __restrict__ receivers, const int* __restrict__ species,
    const float* __restrict__ emb, float* __restrict__ envb, float* __restrict__ Yb,
    float* __restrict__ x72)
{
  const int e = blockIdx.x*256 + threadIdx.x;
  float vx = vectors[e*3+0], vy = vectors[e*3+1], vz = vectors[e*3+2];
  float d = sqrtf(vx*vx+vy*vy+vz*vz);
  float dd = (d==0.f) ? 1.f : d;
  float invd = 1.f/dd;
  float x = vx*invd, y = vy*invd, z = vz*invd;
  float d2=d*d, d3=d2*d, d6=d3*d3, d7=d6*d, d8=d7*d;
  float envv = (d<1.f) ? (1.f - 28.f*d6 + 48.f*d7 - 21.f*d8) : 0.f;
  envb[e] = envv;
  float mask = (d==0.f)?0.f:1.f;
  const float SQ2 = 1.41421356237309515f;
  const float PIf = 3.14159265358979323846f;
  float* xr = x72 + (size_t)e*72;
#pragma unroll
  for (int n=1;n<=8;n++)
    xr[n-1] = SQ2 * sinf((float)n*PIf*dd)*invd*envv*mask;
  int sp_s = species[senders[e]], sp_r = species[receivers[e]];
  const float* es_ = emb + (size_t)sp_s*32;
  const float* er_ = emb + (size_t)sp_r*32;
#pragma unroll 8
  for (int k=0;k<32;k++){ xr[8+k] = es_[k]*mask; xr[40+k] = er_[k]*mask; }
  float x2=x*x, y2=y*y, z2=z*z;
  const float s3=1.7320508075688772f, s15=3.872983346207417f, s5=2.23606797749979f;
  const float s358=2.0916500663351889f, s105=10.246950765959598f;
  const float s218=1.6201851746019651f, s7=2.6457513110645907f;
  float* Yr = Yb + ((size_t)e<<4);
  Yr[0]=1.f;           Yr[1]=s3*y;          Yr[2]=s3*z;           Yr[3]=s3*x;
  Yr[4]=s15*x*y;       Yr[5]=s15*y*z;       Yr[6]=0.5f*s5*(3.f*z2-1.f);
  Yr[7]=s15*x*z;       Yr[8]=0.5f*s15*(x2-y2);
  Yr[9]=s358*y*(3.f*x2-y2);  Yr[10]=s105*x*y*z;  Yr[11]=s218*y*(5.f*z2-1.f);
  Yr[12]=0.5f*s7*(5.f*z2-3.f)*z;  Yr[13]=s218*x*(5.f*z2-1.f);
  Yr[14]=0.5f*s105*(x2-y2)*z;     Yr[15]=s358*x*(x2-y2);
}

// V[e][a*16+m] = w0[e,m]*Y[e,a]  (transposed layout, coalesced writes)
__global__ void vinit_k(const float* __restrict__ w0, const float* __restrict__ Y,
                        float* __restrict__ V)
{
  const int gid = blockIdx.x*256 + threadIdx.x;
  const int e = gid >> 8, idx = gid & 255;
  V[gid] = w0[(e<<4)+(idx&15)] * Y[(e<<4)+(idx>>4)];
}

// node[senders[e]][a*16+m] += w[e,m]*Y[e,a]  (transposed layout)
__global__ void scatter_k(const float* __restrict__ w, const float* __restrict__ Y,
                          const int* __restrict__ senders, float* node)
{
  const int gid = blockIdx.x*256 + threadIdx.x;
  const int e = gid >> 8, idx = gid & 255;
  float v = w[(e<<4) + (idx&15)] * Y[(e<<4) + (idx>>4)];
  atomicAdd(&node[((size_t)senders[e]<<8) + idx], v);
}

// l3=0 TP (slots 0..3), one thread per (e, p*16+m). [a][m] layout:
// element (m,a) at a*16+m -> consecutive-m lanes read coalesced.
__global__ void tp2_k(const float* __restrict__ node, const float* __restrict__ Vn,
    const int* __restrict__ senders, const float* __restrict__ varepsp,
    const int* __restrict__ pmeta, const int* __restrict__ entIJ,
    const float* __restrict__ entVal, float* __restrict__ tp0)
{
  const int gid = blockIdx.x*256 + threadIdx.x;
  const int e = gid >> 6, c = gid & 63;
  const int p = c >> 4, m = c & 15;
  float ve = varepsp[0];
  float eps = rsqrtf(1.f + ve*ve);
  int s = senders[e];
  const float* Am = &node[((size_t)s<<8)];
  const float* Bm = &Vn[((size_t)e<<8)];
  int es = pmeta[p*4+1], ec = pmeta[p*4+2];
  float acc = 0.f;
  for (int t=0;t<ec;t++){
    int ij = entIJ[es+t];
    acc += entVal[es+t] * Am[((ij&255)<<4) + m] * Bm[(((ij>>8)&255)<<4) + m];
  }
  tp0[((size_t)e<<6) + pmeta[p*4+0] + m] = acc * eps;
}

// out[e] = env[e] * dot(X[e,:128], Wout) / sqrt(128)
__global__ void final_k(const float* __restrict__ X, const float* __restrict__ Wout,
                        const float* __restrict__ env, float* __restrict__ out)
{
  const int e = blockIdx.x*256 + threadIdx.x;
  float acc = 0.f;
#pragma unroll 16
  for (int k=0;k<128;k++) acc += X[((size_t)e<<7)+k]*Wout[k];
  out[e] = env[e]*acc*0.088388347648318447f;
}

// ============================ host launcher ============================

static void launch_gemm(int flags, const float* A1, const float* A2, int K1, int K,
    const float* W, int N, float* C, const float* env, const float* alphap,
    const float* Xres, hipStream_t stream)
{
  dim3 grid(E_EDGES/64, (N+63)/64);
  switch(flags){
    case F_NONE:        gemm_k<F_NONE>       <<<grid,256,0,stream>>>(A1,A2,K1,K,W,N,C,env,alphap,Xres); break;
    case F_SILU:        gemm_k<F_SILU>       <<<grid,256,0,stream>>>(A1,A2,K1,K,W,N,C,env,alphap,Xres); break;
    case F_ENV:         gemm_k<F_ENV>        <<<grid,256,0,stream>>>(A1,A2,K1,K,W,N,C,env,alphap,Xres); break;
    case F_ENV|F_RESID: gemm_k<F_ENV|F_RESID><<<grid,256,0,stream>>>(A1,A2,K1,K,W,N,C,env,alphap,Xres); break;
  }
}

static void launch_mgemm(int flags, const float* A1, const float* A2, int K1, int K,
    const unsigned short* Wt, int N, float* C, const float* env, const float* alphap,
    const float* Xres, hipStream_t stream)
{
  dim3 grid(E_EDGES/128, N/128);
  switch(flags){
    case F_NONE:        mgemm_k<F_NONE>       <<<grid,256,0,stream>>>(A1,A2,K1,K,Wt,N,C,env,alphap,Xres); break;
    case F_SILU:        mgemm_k<F_SILU>       <<<grid,256,0,stream>>>(A1,A2,K1,K,Wt,N,C,env,alphap,Xres); break;
    case F_ENV:         mgemm_k<F_ENV>        <<<grid,256,0,stream>>>(A1,A2,K1,K,Wt,N,C,env,alphap,Xres); break;
    case F_ENV|F_RESID: mgemm_k<F_ENV|F_RESID><<<grid,256,0,stream>>>(A1,A2,K1,K,Wt,N,C,env,alphap,Xres); break;
  }
}

extern "C" void kernel_launch(void* const* d_in, const int* in_sizes, int n_in,
                              void* d_out, int out_size, void* d_ws, size_t ws_size,
                              hipStream_t stream)
{
  const float* vectors = (const float*)d_in[0];
  const float* vareps  = (const float*)d_in[1];
  const float* alpha   = (const float*)d_in[2];
  const float* emb     = (const float*)d_in[3];
  const float* W_tb1   = (const float*)d_in[4];
  const float* W_tb2   = (const float*)d_in[5];
  const float* W_tb3   = (const float*)d_in[6];
  const float* W_tb4   = (const float*)d_in[7];
  const float* W_w0    = (const float*)d_in[8];
  const float* W_w1    = (const float*)d_in[9];
  const float* W_l11   = (const float*)d_in[10];
  const float* W_l12   = (const float*)d_in[11];
  const float* W_l13   = (const float*)d_in[12];
  const float* W_v1    = (const float*)d_in[13];
  const float* W_v2    = (const float*)d_in[14];
  const float* W_v3    = (const float*)d_in[15];
  const float* W_w2    = (const float*)d_in[16];
  const float* W_l21   = (const float*)d_in[17];
  const float* W_l22   = (const float*)d_in[18];
  const float* W_l23   = (const float*)d_in[19];
  const float* W_h     = (const float*)d_in[20];
  const float* W_out   = (const float*)d_in[21];
  const int* senders   = (const int*)d_in[22];
  const int* receivers = (const int*)d_in[23];
  const int* species   = (const int*)d_in[24];

  static cgt::Tables tb;
  cgt::build(tb);
  const int Kdim = tb.npairs * 16;

  char* ws = (char*)d_ws;
  size_t off = 0;
  auto alloc = [&](size_t bytes)->void*{
    void* p = ws + off; off += (bytes + 255) & ~(size_t)255; return p;
  };
  float* t_val = (float*)alloc(sizeof(tb.val));
  int*   t_ij  = (int*)  alloc(sizeof(tb.ij));
  int*   t_pm  = (int*)  alloc(sizeof(tb.pmeta));
  float* t_td  = (float*)alloc(sizeof(tb.TD));
  int*   t_pr  = (int*)  alloc(sizeof(tb.pairs));
  int*   t_oc  = (int*)  alloc(sizeof(tb.sl_origc));
  float* envb  = (float*)alloc((size_t)E_EDGES*4);
  float* Yb    = (float*)alloc((size_t)E_EDGES*16*4);
  float* xb    = (float*)alloc((size_t)E_EDGES*256*4);
  float* Vb    = (float*)alloc((size_t)E_EDGES*256*4);   // V, then Vn (in-place)
  float* bufA  = (float*)alloc((size_t)E_EDGES*256*4);
  float* bufB  = (float*)alloc((size_t)E_EDGES*256*4);
  float* wb    = (float*)alloc((size_t)E_EDGES*16*4);
  float* tp0b  = (float*)alloc((size_t)E_EDGES*64*4);
  float* nodeb = (float*)alloc((size_t)NNODES*256*4);
  unsigned short* Gt = (unsigned short*)alloc((size_t)256*Kdim*2);
  unsigned short* Wt_tb3 = (unsigned short*)alloc(64*128*2);
  unsigned short* Wt_tb4 = (unsigned short*)alloc(128*256*2);
  unsigned short* Wt_l11 = (unsigned short*)alloc(320*256*2);
  unsigned short* Wt_l12 = (unsigned short*)alloc(256*256*2);
  unsigned short* Wt_l13 = (unsigned short*)alloc(256*256*2);
  unsigned short* Wt_l21 = (unsigned short*)alloc(320*256*2);
  unsigned short* Wt_l22 = (unsigned short*)alloc(256*256*2);
  unsigned short* Wt_l23 = (unsigned short*)alloc(256*256*2);
  unsigned short* Wt_h   = (unsigned short*)alloc(256*128*2);
  if (off > ws_size) {
    fprintf(stderr, "[allegro] workspace too small: need %zu, have %zu\n", off, ws_size);
    return;
  }

  hipMemcpyAsync(t_val, tb.val,     sizeof(tb.val),     hipMemcpyHostToDevice, stream);
  hipMemcpyAsync(t_ij,  tb.ij,      sizeof(tb.ij),      hipMemcpyHostToDevice, stream);
  hipMemcpyAsync(t_pm,  tb.pmeta,   sizeof(tb.pmeta),   hipMemcpyHostToDevice, stream);
  hipMemcpyAsync(t_td,  tb.TD,      sizeof(tb.TD),      hipMemcpyHostToDevice, stream);
  hipMemcpyAsync(t_pr,  tb.pairs,   sizeof(tb.pairs),   hipMemcpyHostToDevice, stream);
  hipMemcpyAsync(t_oc,  tb.sl_origc,sizeof(tb.sl_origc),hipMemcpyHostToDevice, stream);

  // slot ranges (l3 blocks contiguous in slot order): l1: [s1b,s1e) etc.
  const int s1b = tb.l3np[0];
  const int s1e = s1b + tb.l3np[1];
  const int s2e = s1e + tb.l3np[2];
  const int s3e = s2e + tb.l3np[3];

  // combined coupling x Wv matrix (fp16, tiled [slab][col][32])
  {
    dim3 g((Kdim + 255)/256, 256);
    gbuild_k<<<g, 256, 0, stream>>>(t_td, W_v1, W_v2, W_v3, t_oc, Gt, Kdim,
                                    tb.npairs, s1b, s1e, s2e, s3e);
  }
  // weight convert+transpose (fp16)
  {
    WPack p;
    p.d[0] = { W_tb3, Wt_tb3,  64, 7 };
    p.d[1] = { W_tb4, Wt_tb4, 128, 8 };
    p.d[2] = { W_l11, Wt_l11, 320, 8 };
    p.d[3] = { W_l12, Wt_l12, 256, 8 };
    p.d[4] = { W_l13, Wt_l13, 256, 8 };
    p.d[5] = { W_l21, Wt_l21, 320, 8 };
    p.d[6] = { W_l22, Wt_l22, 256, 8 };
    p.d[7] = { W_h,   Wt_h,   256, 7 };
    p.d[8] = { W_l23, Wt_l23, 256, 8 };
    dim3 g(320, 9);
    wcvt_k<<<g, 256, 0, stream>>>(p);
  }

  // 1. edge features + Y + env
  edge_init_k<<<E_EDGES/256, 256, 0, stream>>>(vectors, senders, receivers, species,
                                               emb, envb, Yb, bufA);
  // 2. two-body MLP: 72 -> 32 -> 64 (fp32) -> 128 -> 256 (fp16 MFMA)
  launch_gemm (F_SILU, bufA, nullptr, 72, 72,  W_tb1, 32,   bufB, envb, alpha, nullptr, stream);
  launch_gemm (F_SILU, bufB, nullptr, 32, 32,  W_tb2, 64,   bufA, envb, alpha, nullptr, stream);
  launch_mgemm(F_SILU, bufA, nullptr, 64, 64,  Wt_tb3, 128, bufB, envb, alpha, nullptr, stream);
  launch_mgemm(F_ENV,  bufB, nullptr, 128,128, Wt_tb4, 256, xb,   envb, alpha, nullptr, stream);
  // 3. V = dense(x,W_w0) outer Y  ([a][m] layout)
  dense16_k<<<E_EDGES/16, 256, 0, stream>>>(xb, W_w0, wb);
  vinit_k<<<E_EDGES, 256, 0, stream>>>(wb, Yb, Vb);

  // ---- layer 1 ----
  dense16_k<<<E_EDGES/16, 256, 0, stream>>>(xb, W_w1, wb);
  hipMemsetAsync(nodeb, 0, (size_t)NNODES*256*4, stream);
  scatter_k<<<E_EDGES, 256, 0, stream>>>(wb, Yb, senders, nodeb);
  // tp0 (l3=0) exact fp32; B = V
  tp2_k<<<E_EDGES*64/256, 256, 0, stream>>>(nodeb, Vb, senders, vareps, t_pm, t_ij,
                                            t_val, tp0b);
  // Vn: fused on-the-fly X + fp16 MFMA (in-place V -> Vn)
  vn_k<<<E_EDGES/VN_E, 256, 0, stream>>>(nodeb, Vb, senders, vareps, t_pr, Gt, Vb, Kdim);
  launch_mgemm(F_SILU,        xb,   tp0b,   256, 320, Wt_l11, 256, bufB, envb, alpha, nullptr, stream);
  launch_mgemm(F_SILU,        bufB, nullptr,256, 256, Wt_l12, 256, bufA, envb, alpha, nullptr, stream);
  launch_mgemm(F_ENV|F_RESID, bufA, nullptr,256, 256, Wt_l13, 256, xb,   envb, alpha, xb,      stream);

  // ---- layer 2 (lmax_out = 0) ----
  dense16_k<<<E_EDGES/16, 256, 0, stream>>>(xb, W_w2, wb);
  hipMemsetAsync(nodeb, 0, (size_t)NNODES*256*4, stream);
  scatter_k<<<E_EDGES, 256, 0, stream>>>(wb, Yb, senders, nodeb);
  tp2_k<<<E_EDGES*64/256, 256, 0, stream>>>(nodeb, Vb, senders, vareps, t_pm, t_ij,
                                            t_val, tp0b);
  launch_mgemm(F_SILU,        xb,   tp0b,   256, 320, Wt_l21, 256, bufB, envb, alpha, nullptr, stream);
  launch_mgemm(F_SILU,        bufB, nullptr,256, 256, Wt_l22, 256, bufA, envb, alpha, nullptr, stream);
  launch_mgemm(F_ENV|F_RESID, bufA, nullptr,256, 256, Wt_l23, 256, xb,   envb, alpha, xb,      stream);

  // ---- head ----
  launch_mgemm(F_NONE, xb, nullptr, 256, 256, Wt_h, 128, bufB, envb, alpha, nullptr, stream);
  final_k<<<E_EDGES/256, 256, 0, stream>>>(bufB, W_out, envb, (float*)d_out);
}

// Round 8
// 583.133 us; speedup vs baseline: 1.7790x; 1.1110x over previous
//
#include <hip/hip_runtime.h>
#include <cmath>
#include <complex>
#include <cstdio>
#include <cstring>
#include <algorithm>

#define E_EDGES 32768
#define NNODES  2048
#define VN_E    32      // edges per vn_k block

// ============================ host-side CG tables ============================
namespace cgt {

static double fct(int n){
  static const double f[13] = {1.,1.,2.,6.,24.,120.,720.,5040.,40320.,362880.,
                               3628800.,39916800.,479001600.};
  return f[n];
}

static double cg(int j1,int m1,int j2,int m2,int j3,int m3){
  if (m1+m2 != m3) return 0.0;
  double pre = std::sqrt((2*j3+1)*fct(j1+j2-j3)*fct(j1-j2+j3)*fct(-j1+j2+j3)/fct(j1+j2+j3+1));
  pre *= std::sqrt(fct(j3+m3)*fct(j3-m3)*fct(j1-m1)*fct(j1+m1)*fct(j2-m2)*fct(j2+m2));
  int kmin = 0;
  if (j2-j3-m1 > kmin) kmin = j2-j3-m1;
  if (j1-j3+m2 > kmin) kmin = j1-j3+m2;
  int kmax = j1+j2-j3;
  if (j1-m1 < kmax) kmax = j1-m1;
  if (j2+m2 < kmax) kmax = j2+m2;
  double s = 0.0;
  for (int k=kmin;k<=kmax;k++){
    double d = fct(k)*fct(j1+j2-j3-k)*fct(j1-m1-k)*fct(j2+m2-k)*fct(j3-j2+m1+k)*fct(j3-j1-m2+k);
    s += ((k&1)? -1.0:1.0)/d;
  }
  return pre*s;
}

typedef std::complex<double> cd;

static void umat(int l, cd U[7][7]){
  for (int a=0;a<7;a++) for (int b=0;b<7;b++) U[a][b]=cd(0,0);
  U[l][l] = cd(1,0);
  double s2 = 1.0/std::sqrt(2.0);
  for (int m=1;m<=l;m++){
    double sg = (m&1)? -1.0 : 1.0;
    U[l+m][l-m] = cd(s2,0);
    U[l+m][l+m] = cd(sg*s2,0);
    U[l-m][l-m] = cd(0, s2);
    U[l-m][l+m] = cd(0, -sg*s2);
  }
}

static bool realCoupling(int l1,int l2,int l3, double T[7][7][7]){
  cd U1[7][7],U2[7][7],U3[7][7];
  umat(l1,U1); umat(l2,U2); umat(l3,U3);
  int n1=2*l1+1, n2=2*l2+1, n3=2*l3+1;
  double Cg[7][7][7];
  for (int m=0;m<n1;m++) for(int n=0;n<n2;n++) for(int k=0;k<n3;k++)
    Cg[m][n][k] = cg(l1,m-l1,l2,n-l2,l3,k-l3);
  double Tr[7][7][7], Ti[7][7][7];
  double nr=0, ni=0;
  for (int a=0;a<n1;a++) for(int b=0;b<n2;b++) for(int c=0;c<n3;c++){
    cd s(0,0);
    for (int m=0;m<n1;m++){
      if (U1[a][m]==cd(0,0)) continue;
      for (int n=0;n<n2;n++){
        if (U2[b][n]==cd(0,0)) continue;
        for (int k=0;k<n3;k++){
          double cgv = Cg[m][n][k];
          if (cgv==0.0) continue;
          s += U1[a][m]*U2[b][n]*std::conj(U3[c][k])*cgv;
        }
      }
    }
    Tr[a][b][c]=s.real(); Ti[a][b][c]=s.imag();
    nr += s.real()*s.real(); ni += s.imag()*s.imag();
  }
  bool useR = (nr >= ni);
  double nn = std::sqrt(useR? nr : ni);
  if (nn < 1e-8) return false;
  for (int a=0;a<n1;a++)for(int b=0;b<n2;b++)for(int c=0;c<n3;c++)
    T[a][b][c] = (useR? Tr[a][b][c] : Ti[a][b][c])/nn;
  return true;
}

struct Tables {
  float val[4096];
  int   ij[4096];        // (a_abs) | (b_abs<<8), entries grouped by (path, c)
  int   pmeta[40*4];     // per SLOT: tpOff(orig layout), entStart, entCount, kdim
  int   ccnt[40*8];      // per SLOT: entry count for each c (kd <= 7)
  int   l3base[4];
  int   l3np[4];
  int   npaths;
  int   nent;
  int   tptot;
  // --- pair/TD tables for the fused Vn GEMM (l>=1 slots only) ---
  int   pairs[256];      // raw (a_abs) | (b_abs<<8)
  float TD[256*30*8];    // TD[pair][slot-4][kloc] = T*sqrt(2l3+1)
  int   sl_origc[40];    // per slot: original c-base (origIdxInL*16) for Wv rows
  int   npairs;          // padded even
};

struct PathTmp {
  int l1,l2,l3, tpoff, kd;
  int ec;                 // total nonzero entries
  double T[7][7][7];
};

static void build(Tables& tb){
  static PathTmp paths[40];
  int np = 0, tpoff = 0;
  int l3start[5];
  for (int l3=0;l3<=3;l3++){
    tb.l3base[l3] = tpoff;
    l3start[l3] = np;
    int kd = 2*l3+1;
    for (int l1=0;l1<=3;l1++) for (int l2=0;l2<=3;l2++){
      int lo = (l1>l2)? l1-l2 : l2-l1;
      int hi = std::min(l1+l2,3);
      if (l3 < lo || l3 > hi) continue;
      PathTmp& pt = paths[np];
      if (!realCoupling(l1,l2,l3,pt.T)) continue;
      pt.l1=l1; pt.l2=l2; pt.l3=l3; pt.kd=kd; pt.tpoff=tpoff;
      double scale = std::sqrt((double)kd);
      int cnt = 0;
      for (int a=0;a<2*l1+1;a++)for(int b=0;b<2*l2+1;b++)for(int c=0;c<kd;c++)
        if (std::fabs(pt.T[a][b][c]*scale) > 1e-7) cnt++;
      pt.ec = cnt;
      tpoff += 16*kd;
      np++;
    }
  }
  l3start[4] = np;
  for (int l3=0;l3<=3;l3++) tb.l3np[l3] = l3start[l3+1]-l3start[l3];
  static int order[40];
  for (int i=0;i<np;i++) order[i]=i;
  for (int l3=0;l3<=3;l3++)
    std::sort(order+l3start[l3], order+l3start[l3+1],
              [&](int a,int b){ return paths[a].ec > paths[b].ec; });
  // emit entries grouped by (slot, c); build pair map + TD for l>=1 slots
  std::memset(tb.TD, 0, sizeof(tb.TD));
  std::memset(tb.pairs, 0, sizeof(tb.pairs));
  static int pmap[16][16];
  for (int i=0;i<16;i++) for (int j=0;j<16;j++) pmap[i][j] = -1;
  int npr = 0;
  int ep = 0;
  for (int slot=0; slot<np; slot++){
    const PathTmp& pt = paths[order[slot]];
    double scale = std::sqrt((double)pt.kd);
    int s1 = pt.l1*pt.l1, s2 = pt.l2*pt.l2;
    tb.pmeta[slot*4+0] = pt.tpoff;
    tb.pmeta[slot*4+1] = ep;
    tb.sl_origc[slot] = ((pt.tpoff - tb.l3base[pt.l3]) / (16*pt.kd)) * 16;
    int tot = 0;
    for (int c=0;c<pt.kd;c++){
      int cnt = 0;
      for (int a=0;a<2*pt.l1+1;a++)for(int b=0;b<2*pt.l2+1;b++){
        double v = pt.T[a][b][c]*scale;
        if (std::fabs(v) > 1e-7){
          tb.val[ep] = (float)v;
          tb.ij[ep]  = (s1+a) | ((s2+b)<<8);
          ep++; cnt++;
          if (pt.l3 >= 1){
            int aa = s1+a, bb = s2+b;
            int pi = pmap[aa][bb];
            if (pi < 0){ pi = npr; pmap[aa][bb] = pi;
                         tb.pairs[npr] = aa | (bb<<8); npr++; }
            tb.TD[(pi*30 + (slot-4))*8 + c] = (float)v;
          }
        }
      }
      tb.ccnt[slot*8+c] = cnt;
      tot += cnt;
    }
    for (int c=pt.kd;c<8;c++) tb.ccnt[slot*8+c]=0;
    tb.pmeta[slot*4+2] = tot;
    tb.pmeta[slot*4+3] = pt.kd;
  }
  if (npr & 1){ tb.pairs[npr] = 0; npr++; }   // pad to even -> Kdim % 32 == 0
  tb.npairs = npr;
  tb.npaths = np; tb.nent = ep; tb.tptot = tpoff;
}

} // namespace cgt

// ============================ device kernels ============================
// LAYOUT CONVENTION: node/V/Vn rows are [a][m] (spherical-major,
// element (m,a) at a*16+m).

enum GFlags { F_NONE=0, F_SILU=1, F_ENV=2, F_RESID=4 };

typedef _Float16 half8 __attribute__((ext_vector_type(8)));
typedef _Float16 half4 __attribute__((ext_vector_type(4)));
typedef __attribute__((ext_vector_type(4))) float f32x4;

__device__ inline unsigned short f2h(float f){
  union { _Float16 h; unsigned short u; } x;
  x.h = (_Float16)f;           // v_cvt_f16_f32, RNE
  return x.u;
}
__device__ inline float h2f(unsigned short u){
  union { _Float16 h; unsigned short u; } x; x.u = u;
  return (float)x.h;
}

// XOR swizzle for 64B-row LDS tiles of 16-bit data: permutes 16B units so
// ds_read_b128 fragment loads are ~conflict-free. kh in ushort units (mult of 4).
__device__ inline int swz(int row, int kh){
  int b = row*64 + kh*2;
  return b ^ (((row >> 1) & 3) << 4);
}

// ---- fp16 MFMA GEMM: C[M,N] = post( A[M,K] @ W[K,N] / sqrt(K) ), A fp32 ----
template<int FLAGS>
__global__ __launch_bounds__(256) void mgemm_k(
    const float* __restrict__ A1, const float* __restrict__ A2,
    int K1, int K, const unsigned short* __restrict__ Wt, int N,
    float* Cout, const float* __restrict__ env,
    const float* __restrict__ alphap, const float* Xres)
{
  __shared__ unsigned short AsB[128*32];
  __shared__ unsigned short BsB[128*32];
  const int tid  = threadIdx.x;
  const int wave = tid >> 6, lane = tid & 63;
  const int bm = blockIdx.x*128, bn = blockIdx.y*128;
  const int wr = (wave >> 1)*64, wc = (wave & 1)*64;
  const int K2 = K - K1;
  f32x4 acc[4][4] = {};

  const int sr  = tid >> 3;          // staging row 0..31 (A)
  const int skq = (tid & 7) * 4;     // staging k 0..28 step 4 (A)
  const int bn_ = tid >> 1;          // staging n 0..127 (B)
  const int bkh = (tid & 1) * 16;    // staging k half (B)

  for (int k0 = 0; k0 < K; k0 += 32) {
#pragma unroll
    for (int q = 0; q < 4; q++) {
      int row = q*32 + sr;
      int grow = bm + row;
      int kk = k0 + skq;
      float4 f4 = (kk < K1) ? *(const float4*)(A1 + (size_t)grow*K1 + kk)
                            : *(const float4*)(A2 + (size_t)grow*K2 + (kk - K1));
      ushort4 u;
      u.x = f2h(f4.x); u.y = f2h(f4.y); u.z = f2h(f4.z); u.w = f2h(f4.w);
      *(ushort4*)((char*)AsB + swz(row, skq)) = u;
    }
    {
      const unsigned short* s = Wt + (size_t)(bn + bn_)*K + k0 + bkh;
#pragma unroll
      for (int q = 0; q < 4; q++) {
        ushort4 u = *(const ushort4*)(s + q*4);
        *(ushort4*)((char*)BsB + swz(bn_, bkh + q*4)) = u;
      }
    }
    __syncthreads();
    const int fr = lane & 15, fk = (lane >> 4) * 8;
    half8 af[4], bf[4];
#pragma unroll
    for (int i = 0; i < 4; i++)
      af[i] = *(half8*)((char*)AsB + swz(wr + i*16 + fr, fk));
#pragma unroll
    for (int j = 0; j < 4; j++)
      bf[j] = *(half8*)((char*)BsB + swz(wc + j*16 + fr, fk));
#pragma unroll
    for (int i = 0; i < 4; i++)
#pragma unroll
      for (int j = 0; j < 4; j++)
        acc[i][j] = __builtin_amdgcn_mfma_f32_16x16x32_f16(af[i], bf[j], acc[i][j], 0, 0, 0);
    __syncthreads();
  }

  const float rscale = 1.f/sqrtf((float)K);
  float a2 = 0.f, inv1a2 = 1.f;
  if (FLAGS & F_RESID) { float al = alphap[0]; a2 = al*al; inv1a2 = 1.f/(1.f+a2); }
#pragma unroll
  for (int i = 0; i < 4; i++) {
#pragma unroll
    for (int r = 0; r < 4; r++) {
      int row = bm + wr + i*16 + ((lane >> 4) << 2) + r;
      float ev = (FLAGS & F_ENV) ? env[row] : 1.f;
#pragma unroll
      for (int j = 0; j < 4; j++) {
        int col = bn + wc + j*16 + (lane & 15);
        float v = acc[i][j][r]*rscale;
        if (FLAGS & F_SILU) v = v/(1.f+__expf(-v));
        if (FLAGS & F_ENV)  v *= ev;
        if (FLAGS & F_RESID) v = (Xres[(size_t)row*N+col] + a2*v)*inv1a2;
        Cout[(size_t)row*N+col] = v;
      }
    }
  }
}

// ---- fused Vn kernel v3: barrier-free K-loop ----
// Vn[e, kabs*16+d] = sum_k X[e,k]*G[k,col]; X[(pair,m)] = (eps*node[s])(m,a)*V[e](m,b).
// R7 fix (latency-bound: MfmaUtil 13%, all pipes idle, 2 barriers x 75 slabs):
//  - consumer lane computes its OWN A-fragment from Ab/Bb (2x ds_read_b128 +
//    pk_mul) -> X never in LDS, no producer barrier;
//  - wave w owns cols w*64..w*64+63; G fragments loaded straight from global
//    ([slab][col][32] tiling -> each wave's 4 loads = coalesced 1KB from L2);
//  - 2-deep register prefetch of next slab's G frags; zero __syncthreads in loop;
//  - LDS 53K -> ~35K => 4 blocks/CU (16 waves) for latency hiding.
__global__ __launch_bounds__(256) void vn_k(
    const float* __restrict__ node, const float* __restrict__ V,
    const int* __restrict__ senders, const float* __restrict__ varepsp,
    const int* __restrict__ pairsG, const unsigned short* __restrict__ Gtt,
    float* __restrict__ Vn, int Kdim)
{
  __shared__ unsigned short Ab[VN_E*264];   // fp16 eps*node rows, pad 264
  __shared__ unsigned short Bb[VN_E*264];   // fp16 V rows
  __shared__ int Ps[256];
  const int tid = threadIdx.x;
  const int e0 = blockIdx.x * VN_E;
  float ve = varepsp[0];
  float eps = rsqrtf(1.f + ve*ve);
  Ps[tid] = pairsG[tid];
  {
    int row = tid >> 3;            // 0..31
    int seg = (tid & 7) * 32;      // 0..224
    int s = senders[e0 + row];
    const float* ap = node + ((size_t)s << 8) + seg;
    const float* bp = V + (((size_t)(e0 + row)) << 8) + seg;
    unsigned short* ad = Ab + row*264 + seg;
    unsigned short* bd = Bb + row*264 + seg;
#pragma unroll
    for (int q = 0; q < 8; q++) {
      float4 fa = *(const float4*)(ap + q*4);
      float4 fb = *(const float4*)(bp + q*4);
      *(unsigned*)(ad + q*4)     = (unsigned)f2h(fa.x*eps) | ((unsigned)f2h(fa.y*eps) << 16);
      *(unsigned*)(ad + q*4 + 2) = (unsigned)f2h(fa.z*eps) | ((unsigned)f2h(fa.w*eps) << 16);
      *(unsigned*)(bd + q*4)     = (unsigned)f2h(fb.x) | ((unsigned)f2h(fb.y) << 16);
      *(unsigned*)(bd + q*4 + 2) = (unsigned)f2h(fb.z) | ((unsigned)f2h(fb.w) << 16);
    }
  }
  __syncthreads();
  const int wave = tid >> 6, lane = tid & 63;
  const int wc = wave * 64;              // 64 output cols per wave
  const int fr = lane & 15, fk = (lane >> 4) * 8;
  const int pairSel = fk >> 4;           // 0 or 1 (which pair of the slab)
  const int moff = fk & 15;              // 0 or 8 (m offset within pair)
  const int nslab = Kdim >> 5;
  f32x4 acc[2][4] = {};                  // [row group 0/16][j]

  // G fragment base for this lane: element ((sl*256 + wc + j*16 + fr)*32 + fk)
  const unsigned short* gp = Gtt + ((size_t)(wc + fr)) * 32 + fk;
  half8 b0 = *(const half8*)(gp);
  half8 b1 = *(const half8*)(gp + 512);
  half8 b2 = *(const half8*)(gp + 1024);
  half8 b3 = *(const half8*)(gp + 1536);

  for (int sl = 0; sl < nslab; sl++) {
    // A fragments: lane's own 8 consecutive-m X values for its k-slice
    int p = Ps[2*sl + pairSel];
    int aoff = ((p & 255) << 4) + moff;
    int boff = (((p >> 8) & 255) << 4) + moff;
    half8 a0 = (*(const half8*)(Ab + fr*264 + aoff)) *
               (*(const half8*)(Bb + fr*264 + boff));
    half8 a1 = (*(const half8*)(Ab + (16 + fr)*264 + aoff)) *
               (*(const half8*)(Bb + (16 + fr)*264 + boff));
    // prefetch next slab's G fragments
    half8 n0, n1, n2, n3;
    if (sl + 1 < nslab) {
      const unsigned short* gn = gp + (size_t)(sl + 1) * 8192;
      n0 = *(const half8*)(gn);
      n1 = *(const half8*)(gn + 512);
      n2 = *(const half8*)(gn + 1024);
      n3 = *(const half8*)(gn + 1536);
    } else { n0 = b0; n1 = b1; n2 = b2; n3 = b3; }
    acc[0][0] = __builtin_amdgcn_mfma_f32_16x16x32_f16(a0, b0, acc[0][0], 0, 0, 0);
    acc[1][0] = __builtin_amdgcn_mfma_f32_16x16x32_f16(a1, b0, acc[1][0], 0, 0, 0);
    acc[0][1] = __builtin_amdgcn_mfma_f32_16x16x32_f16(a0, b1, acc[0][1], 0, 0, 0);
    acc[1][1] = __builtin_amdgcn_mfma_f32_16x16x32_f16(a1, b1, acc[1][1], 0, 0, 0);
    acc[0][2] = __builtin_amdgcn_mfma_f32_16x16x32_f16(a0, b2, acc[0][2], 0, 0, 0);
    acc[1][2] = __builtin_amdgcn_mfma_f32_16x16x32_f16(a1, b2, acc[1][2], 0, 0, 0);
    acc[0][3] = __builtin_amdgcn_mfma_f32_16x16x32_f16(a0, b3, acc[0][3], 0, 0, 0);
    acc[1][3] = __builtin_amdgcn_mfma_f32_16x16x32_f16(a1, b3, acc[1][3], 0, 0, 0);
    b0 = n0; b1 = n1; b2 = n2; b3 = n3;
  }
  const int r4 = (lane >> 4) << 2;
#pragma unroll
  for (int rg = 0; rg < 2; rg++) {
#pragma unroll
    for (int j = 0; j < 4; j++) {
#pragma unroll
      for (int r = 0; r < 4; r++) {
        int row = e0 + rg*16 + r4 + r;
        int col = wc + j*16 + fr;
        Vn[(size_t)row*256 + col] = acc[rg][j][r];
      }
    }
  }
}

// ---- Gtt[slab][col][32] = coupling x Wv (fp16, tiled). col = kabs*16+d ----
__global__ void gbuild_k(const float* __restrict__ TD,
    const float* __restrict__ Wv1, const float* __restrict__ Wv2,
    const float* __restrict__ Wv3, const int* __restrict__ sl_origc,
    unsigned short* __restrict__ Gt, int Kdim, int npairs,
    int s1b, int s1e, int s2e, int s3e)
{
  int k = blockIdx.x*256 + threadIdx.x;
  if (k >= Kdim) return;
  int col = blockIdx.y;
  int pair = k >> 4, m = k & 15;
  int d = col & 15, kabs = col >> 4;     // transposed output convention
  float acc = 0.f;
  if (kabs > 0 && pair < npairs) {
    const float* Wv; int ss, se, kloc;
    if (kabs < 4)      { Wv = Wv1; ss = s1b; se = s1e; kloc = kabs - 1; }
    else if (kabs < 9) { Wv = Wv2; ss = s1e; se = s2e; kloc = kabs - 4; }
    else               { Wv = Wv3; ss = s2e; se = s3e; kloc = kabs - 9; }
    for (int slot = ss; slot < se; slot++)
      acc += TD[((pair*30) + (slot - 4))*8 + kloc] * Wv[(sl_origc[slot] + m)*16 + d];
    acc *= rsqrtf((float)(16*(se - ss)));
  }
  Gt[((size_t)((k >> 5)*256 + col))*32 + (k & 31)] = f2h(acc);
}

// ---- weight convert + transpose: Wt[n][k] = fp16(W[k][n]) ----
struct WDesc { const float* src; unsigned short* dst; int K; int lgN; };
struct WPack { WDesc d[9]; };
__global__ void wcvt_k(WPack p){
  WDesc d = p.d[blockIdx.y];
  int total = d.K << d.lgN;
  int gid = blockIdx.x*256 + threadIdx.x;
  if (gid >= total) return;
  int k = gid >> d.lgN, n = gid & ((1 << d.lgN) - 1);
  d.dst[(size_t)n*d.K + k] = f2h(d.src[gid]);
}

// Generic fp32 tiled GEMM (small two-body layers).
template<int FLAGS>
__global__ __launch_bounds__(256) void gemm_k(
    const float* __restrict__ A1, const float* __restrict__ A2,
    int K1, int K, const float* __restrict__ W, int N,
    float* Cout,
    const float* __restrict__ env, const float* __restrict__ alphap,
    const float* Xres)
{
  __shared__ float As[16][68];
  __shared__ float Ws[16][68];
  const int tid = threadIdx.x;
  const int bm = blockIdx.x * 64;
  const int bn = blockIdx.y * 64;
  const int tx = tid & 15, ty = tid >> 4;
  const int K2 = K - K1;
  float acc[4][4] = {};
  for (int k0 = 0; k0 < K; k0 += 16) {
#pragma unroll
    for (int i = 0; i < 4; i++) {
      int idx = tid + i*256;
      int m = idx >> 4, kk = idx & 15;
      int k = k0 + kk;
      float v = 0.f;
      if (k < K) {
        int row = bm + m;
        v = (k < K1) ? A1[(size_t)row*K1 + k] : A2[(size_t)row*K2 + (k-K1)];
      }
      As[kk][m] = v;
    }
#pragma unroll
    for (int i = 0; i < 4; i++) {
      int idx = tid + i*256;
      int n = idx & 63, kk = idx >> 6;
      int k = k0 + kk, col = bn + n;
      Ws[kk][n] = (k < K && col < N) ? W[(size_t)k*N + col] : 0.f;
    }
    __syncthreads();
#pragma unroll
    for (int kk = 0; kk < 16; kk++) {
      float a[4], b[4];
#pragma unroll
      for (int i=0;i<4;i++) a[i] = As[kk][ty*4+i];
#pragma unroll
      for (int j=0;j<4;j++) b[j] = Ws[kk][tx*4+j];
#pragma unroll
      for (int i=0;i<4;i++)
#pragma unroll
        for (int j=0;j<4;j++)
          acc[i][j] += a[i]*b[j];
    }
    __syncthreads();
  }
  const float rscale = 1.f/sqrtf((float)K);
  float a2 = 0.f, inv1a2 = 1.f;
  if (FLAGS & F_RESID) { float al = alphap[0]; a2 = al*al; inv1a2 = 1.f/(1.f+a2); }
#pragma unroll
  for (int i=0;i<4;i++) {
    int row = bm + ty*4 + i;
    float ev = (FLAGS & F_ENV) ? env[row] : 1.f;
#pragma unroll
    for (int j=0;j<4;j++) {
      int col = bn + tx*4 + j;
      if (col >= N) continue;
      float v = acc[i][j]*rscale;
      if (FLAGS & F_SILU) v = v/(1.f+__expf(-v));
      if (FLAGS & F_ENV)  v *= ev;
      if (FLAGS & F_RESID) v = (Xres[(size_t)row*N+col] + a2*v)*inv1a2;
      Cout[(size_t)row*N+col] = v;
    }
  }
}

// dense to 16 outputs, K=256 fixed, scale 1/16
__global__ __launch_bounds__(256) void dense16_k(const float* __restrict__ A,
    const float* __restrict__ W, float* __restrict__ C)
{
  __shared__ float As[16*256];
  const int r0 = blockIdx.x << 4;
  const int tid = threadIdx.x;
  for (int i = tid; i < 16*256; i += 256)
    As[i] = A[((size_t)r0<<8) + i];
  __syncthreads();
  const int r = tid >> 4, n = tid & 15;
  float acc = 0.f;
#pragma unroll 8
  for (int k = 0; k < 256; k++)
    acc += As[(r<<8)+k] * W[(k<<4)+n];
  C[((size_t)(r0+r)<<4)+n] = acc * 0.0625f;
}

__global__ void edge_init_k(const float* __restrict__ vectors, const int* __restrict__ senders,
    const int* __restrict__ receivers, const int* __restrict__ species,
    const float* __restrict__ emb, float* __restrict__ envb, float* __restrict__ Yb,
    float* __restrict__ x72)
{
  const int e = blockIdx.x*256 + threadIdx.x;
  float vx = vectors[e*3+0], vy = vectors[e*3+1], vz = vectors[e*3+2];
  float d = sqrtf(vx*vx+vy*vy+vz*vz);
  float dd = (d==0.f) ? 1.f : d;
  float invd = 1.f/dd;
  float x = vx*invd, y = vy*invd, z = vz*invd;
  float d2=d*d, d3=d2*d, d6=d3*d3, d7=d6*d, d8=d7*d;
  float envv = (d<1.f) ? (1.f - 28.f*d6 + 48.f*d7 - 21.f*d8) : 0.f;
  envb[e] = envv;
  float mask = (d==0.f)?0.f:1.f;
  const float SQ2 = 1.41421356237309515f;
  const float PIf = 3.14159265358979323846f;
  float* xr = x72 + (size_t)e*72;
#pragma unroll
  for (int n=1;n<=8;n++)
    xr[n-1] = SQ2 * sinf((float)n*PIf*dd)*invd*envv*mask;
  int sp_s = species[senders[e]], sp_r = species[receivers[e]];
  const float* es_ = emb + (size_t)sp_s*32;
  const float* er_ = emb + (size_t)sp_r*32;
#pragma unroll 8
  for (int k=0;k<32;k++){ xr[8+k] = es_[k]*mask; xr[40+k] = er_[k]*mask; }
  float x2=x*x, y2=y*y, z2=z*z;
  const float s3=1.7320508075688772f, s15=3.872983346207417f, s5=2.23606797749979f;
  const float s358=2.0916500663351889f, s105=10.246950765959598f;
  const float s218=1.6201851746019651f, s7=2.6457513110645907f;
  float* Yr = Yb + ((size_t)e<<4);
  Yr[0]=1.f;           Yr[1]=s3*y;          Yr[2]=s3*z;           Yr[3]=s3*x;
  Yr[4]=s15*x*y;       Yr[5]=s15*y*z;       Yr[6]=0.5f*s5*(3.f*z2-1.f);
  Yr[7]=s15*x*z;       Yr[8]=0.5f*s15*(x2-y2);
  Yr[9]=s358*y*(3.f*x2-y2);  Yr[10]=s105*x*y*z;  Yr[11]=s218*y*(5.f*z2-1.f);
  Yr[12]=0.5f*s7*(5.f*z2-3.f)*z;  Yr[13]=s218*x*(5.f*z2-1.f);
  Yr[14]=0.5f*s105*(x2-y2)*z;     Yr[15]=s358*x*(x2-y2);
}

// V[e][a*16+m] = w0[e,m]*Y[e,a]  (transposed layout, coalesced writes)
__global__ void vinit_k(const float* __restrict__ w0, const float* __restrict__ Y,
                        float* __restrict__ V)
{
  const int gid = blockIdx.x*256 + threadIdx.x;
  const int e = gid >> 8, idx = gid & 255;
  V[gid] = w0[(e<<4)+(idx&15)] * Y[(e<<4)+(idx>>4)];
}

// node[senders[e]][a*16+m] += w[e,m]*Y[e,a]  (transposed layout)
__global__ void scatter_k(const float* __restrict__ w, const float* __restrict__ Y,
                          const int* __restrict__ senders, float* node)
{
  const int gid = blockIdx.x*256 + threadIdx.x;
  const int e = gid >> 8, idx = gid & 255;
  float v = w[(e<<4) + (idx&15)] * Y[(e<<4) + (idx>>4)];
  atomicAdd(&node[((size_t)senders[e]<<8) + idx], v);
}

// l3=0 TP (slots 0..3), one thread per (e, p*16+m). [a][m] layout:
// element (m,a) at a*16+m -> consecutive-m lanes read coalesced.
__global__ void tp2_k(const float* __restrict__ node, const float* __restrict__ Vn,
    const int* __restrict__ senders, const float* __restrict__ varepsp,
    const int* __restrict__ pmeta, const int* __restrict__ entIJ,
    const float* __restrict__ entVal, float* __restrict__ tp0)
{
  const int gid = blockIdx.x*256 + threadIdx.x;
  const int e = gid >> 6, c = gid & 63;
  const int p = c >> 4, m = c & 15;
  float ve = varepsp[0];
  float eps = rsqrtf(1.f + ve*ve);
  int s = senders[e];
  const float* Am = &node[((size_t)s<<8)];
  const float* Bm = &Vn[((size_t)e<<8)];
  int es = pmeta[p*4+1], ec = pmeta[p*4+2];
  float acc = 0.f;
  for (int t=0;t<ec;t++){
    int ij = entIJ[es+t];
    acc += entVal[es+t] * Am[((ij&255)<<4) + m] * Bm[(((ij>>8)&255)<<4) + m];
  }
  tp0[((size_t)e<<6) + pmeta[p*4+0] + m] = acc * eps;
}

// out[e] = env[e] * dot(X[e,:128], Wout) / sqrt(128)
__global__ void final_k(const float* __restrict__ X, const float* __restrict__ Wout,
                        const float* __restrict__ env, float* __restrict__ out)
{
  const int e = blockIdx.x*256 + threadIdx.x;
  float acc = 0.f;
#pragma unroll 16
  for (int k=0;k<128;k++) acc += X[((size_t)e<<7)+k]*Wout[k];
  out[e] = env[e]*acc*0.088388347648318447f;
}

// ============================ host launcher ============================

static void launch_gemm(int flags, const float* A1, const float* A2, int K1, int K,
    const float* W, int N, float* C, const float* env, const float* alphap,
    const float* Xres, hipStream_t stream)
{
  dim3 grid(E_EDGES/64, (N+63)/64);
  switch(flags){
    case F_NONE:        gemm_k<F_NONE>       <<<grid,256,0,stream>>>(A1,A2,K1,K,W,N,C,env,alphap,Xres); break;
    case F_SILU:        gemm_k<F_SILU>       <<<grid,256,0,stream>>>(A1,A2,K1,K,W,N,C,env,alphap,Xres); break;
    case F_ENV:         gemm_k<F_ENV>        <<<grid,256,0,stream>>>(A1,A2,K1,K,W,N,C,env,alphap,Xres); break;
    case F_ENV|F_RESID: gemm_k<F_ENV|F_RESID><<<grid,256,0,stream>>>(A1,A2,K1,K,W,N,C,env,alphap,Xres); break;
  }
}

static void launch_mgemm(int flags, const float* A1, const float* A2, int K1, int K,
    const unsigned short* Wt, int N, float* C, const float* env, const float* alphap,
    const float* Xres, hipStream_t stream)
{
  dim3 grid(E_EDGES/128, N/128);
  switch(flags){
    case F_NONE:        mgemm_k<F_NONE>       <<<grid,256,0,stream>>>(A1,A2,K1,K,Wt,N,C,env,alphap,Xres); break;
    case F_SILU:        mgemm_k<F_SILU>       <<<grid,256,0,stream>>>(A1,A2,K1,K,Wt,N,C,env,alphap,Xres); break;
    case F_ENV:         mgemm_k<F_ENV>        <<<grid,256,0,stream>>>(A1,A2,K1,K,Wt,N,C,env,alphap,Xres); break;
    case F_ENV|F_RESID: mgemm_k<F_ENV|F_RESID><<<grid,256,0,stream>>>(A1,A2,K1,K,Wt,N,C,env,alphap,Xres); break;
  }
}

extern "C" void kernel_launch(void* const* d_in, const int* in_sizes, int n_in,
                              void* d_out, int out_size, void* d_ws, size_t ws_size,
                              hipStream_t stream)
{
  const float* vectors = (const float*)d_in[0];
  const float* vareps  = (const float*)d_in[1];
  const float* alpha   = (const float*)d_in[2];
  const float* emb     = (const float*)d_in[3];
  const float* W_tb1   = (const float*)d_in[4];
  const float* W_tb2   = (const float*)d_in[5];
  const float* W_tb3   = (const float*)d_in[6];
  const float* W_tb4   = (const float*)d_in[7];
  const float* W_w0    = (const float*)d_in[8];
  const float* W_w1    = (const float*)d_in[9];
  const float* W_l11   = (const float*)d_in[10];
  const float* W_l12   = (const float*)d_in[11];
  const float* W_l13   = (const float*)d_in[12];
  const float* W_v1    = (const float*)d_in[13];
  const float* W_v2    = (const float*)d_in[14];
  const float* W_v3    = (const float*)d_in[15];
  const float* W_w2    = (const float*)d_in[16];
  const float* W_l21   = (const float*)d_in[17];
  const float* W_l22   = (const float*)d_in[18];
  const float* W_l23   = (const float*)d_in[19];
  const float* W_h     = (const float*)d_in[20];
  const float* W_out   = (const float*)d_in[21];
  const int* senders   = (const int*)d_in[22];
  const int* receivers = (const int*)d_in[23];
  const int* species   = (const int*)d_in[24];

  static cgt::Tables tb;
  cgt::build(tb);
  const int Kdim = tb.npairs * 16;

  char* ws = (char*)d_ws;
  size_t off = 0;
  auto alloc = [&](size_t bytes)->void*{
    void* p = ws + off; off += (bytes + 255) & ~(size_t)255; return p;
  };
  float* t_val = (float*)alloc(sizeof(tb.val));
  int*   t_ij  = (int*)  alloc(sizeof(tb.ij));
  int*   t_pm  = (int*)  alloc(sizeof(tb.pmeta));
  float* t_td  = (float*)alloc(sizeof(tb.TD));
  int*   t_pr  = (int*)  alloc(sizeof(tb.pairs));
  int*   t_oc  = (int*)  alloc(sizeof(tb.sl_origc));
  float* envb  = (float*)alloc((size_t)E_EDGES*4);
  float* Yb    = (float*)alloc((size_t)E_EDGES*16*4);
  float* xb    = (float*)alloc((size_t)E_EDGES*256*4);
  float* Vb    = (float*)alloc((size_t)E_EDGES*256*4);   // V, then Vn (in-place)
  float* bufA  = (float*)alloc((size_t)E_EDGES*256*4);
  float* bufB  = (float*)alloc((size_t)E_EDGES*256*4);
  float* wb    = (float*)alloc((size_t)E_EDGES*16*4);
  float* tp0b  = (float*)alloc((size_t)E_EDGES*64*4);
  float* nodeb = (float*)alloc((size_t)NNODES*256*4);
  unsigned short* Gt = (unsigned short*)alloc((size_t)256*Kdim*2);
  unsigned short* Wt_tb3 = (unsigned short*)alloc(64*128*2);
  unsigned short* Wt_tb4 = (unsigned short*)alloc(128*256*2);
  unsigned short* Wt_l11 = (unsigned short*)alloc(320*256*2);
  unsigned short* Wt_l12 = (unsigned short*)alloc(256*256*2);
  unsigned short* Wt_l13 = (unsigned short*)alloc(256*256*2);
  unsigned short* Wt_l21 = (unsigned short*)alloc(320*256*2);
  unsigned short* Wt_l22 = (unsigned short*)alloc(256*256*2);
  unsigned short* Wt_l23 = (unsigned short*)alloc(256*256*2);
  unsigned short* Wt_h   = (unsigned short*)alloc(256*128*2);
  if (off > ws_size) {
    fprintf(stderr, "[allegro] workspace too small: need %zu, have %zu\n", off, ws_size);
    return;
  }

  hipMemcpyAsync(t_val, tb.val,     sizeof(tb.val),     hipMemcpyHostToDevice, stream);
  hipMemcpyAsync(t_ij,  tb.ij,      sizeof(tb.ij),      hipMemcpyHostToDevice, stream);
  hipMemcpyAsync(t_pm,  tb.pmeta,   sizeof(tb.pmeta),   hipMemcpyHostToDevice, stream);
  hipMemcpyAsync(t_td,  tb.TD,      sizeof(tb.TD),      hipMemcpyHostToDevice, stream);
  hipMemcpyAsync(t_pr,  tb.pairs,   sizeof(tb.pairs),   hipMemcpyHostToDevice, stream);
  hipMemcpyAsync(t_oc,  tb.sl_origc,sizeof(tb.sl_origc),hipMemcpyHostToDevice, stream);

  // slot ranges (l3 blocks contiguous in slot order): l1: [s1b,s1e) etc.
  const int s1b = tb.l3np[0];
  const int s1e = s1b + tb.l3np[1];
  const int s2e = s1e + tb.l3np[2];
  const int s3e = s2e + tb.l3np[3];

  // combined coupling x Wv matrix (fp16, tiled [slab][col][32])
  {
    dim3 g((Kdim + 255)/256, 256);
    gbuild_k<<<g, 256, 0, stream>>>(t_td, W_v1, W_v2, W_v3, t_oc, Gt, Kdim,
                                    tb.npairs, s1b, s1e, s2e, s3e);
  }
  // weight convert+transpose (fp16)
  {
    WPack p;
    p.d[0] = { W_tb3, Wt_tb3,  64, 7 };
    p.d[1] = { W_tb4, Wt_tb4, 128, 8 };
    p.d[2] = { W_l11, Wt_l11, 320, 8 };
    p.d[3] = { W_l12, Wt_l12, 256, 8 };
    p.d[4] = { W_l13, Wt_l13, 256, 8 };
    p.d[5] = { W_l21, Wt_l21, 320, 8 };
    p.d[6] = { W_l22, Wt_l22, 256, 8 };
    p.d[7] = { W_h,   Wt_h,   256, 7 };
    p.d[8] = { W_l23, Wt_l23, 256, 8 };
    dim3 g(320, 9);
    wcvt_k<<<g, 256, 0, stream>>>(p);
  }

  // 1. edge features + Y + env
  edge_init_k<<<E_EDGES/256, 256, 0, stream>>>(vectors, senders, receivers, species,
                                               emb, envb, Yb, bufA);
  // 2. two-body MLP: 72 -> 32 -> 64 (fp32) -> 128 -> 256 (fp16 MFMA)
  launch_gemm (F_SILU, bufA, nullptr, 72, 72,  W_tb1, 32,   bufB, envb, alpha, nullptr, stream);
  launch_gemm (F_SILU, bufB, nullptr, 32, 32,  W_tb2, 64,   bufA, envb, alpha, nullptr, stream);
  launch_mgemm(F_SILU, bufA, nullptr, 64, 64,  Wt_tb3, 128, bufB, envb, alpha, nullptr, stream);
  launch_mgemm(F_ENV,  bufB, nullptr, 128,128, Wt_tb4, 256, xb,   envb, alpha, nullptr, stream);
  // 3. V = dense(x,W_w0) outer Y  ([a][m] layout)
  dense16_k<<<E_EDGES/16, 256, 0, stream>>>(xb, W_w0, wb);
  vinit_k<<<E_EDGES, 256, 0, stream>>>(wb, Yb, Vb);

  // ---- layer 1 ----
  dense16_k<<<E_EDGES/16, 256, 0, stream>>>(xb, W_w1, wb);
  hipMemsetAsync(nodeb, 0, (size_t)NNODES*256*4, stream);
  scatter_k<<<E_EDGES, 256, 0, stream>>>(wb, Yb, senders, nodeb);
  // tp0 (l3=0) exact fp32; B = V
  tp2_k<<<E_EDGES*64/256, 256, 0, stream>>>(nodeb, Vb, senders, vareps, t_pm, t_ij,
                                            t_val, tp0b);
  // Vn: fused on-the-fly X + fp16 MFMA (in-place V -> Vn), barrier-free loop
  vn_k<<<E_EDGES/VN_E, 256, 0, stream>>>(nodeb, Vb, senders, vareps, t_pr, Gt, Vb, Kdim);
  launch_mgemm(F_SILU,        xb,   tp0b,   256, 320, Wt_l11, 256, bufB, envb, alpha, nullptr, stream);
  launch_mgemm(F_SILU,        bufB, nullptr,256, 256, Wt_l12, 256, bufA, envb, alpha, nullptr, stream);
  launch_mgemm(F_ENV|F_RESID, bufA, nullptr,256, 256, Wt_l13, 256, xb,   envb, alpha, xb,      stream);

  // ---- layer 2 (lmax_out = 0) ----
  dense16_k<<<E_EDGES/16, 256, 0, stream>>>(xb, W_w2, wb);
  hipMemsetAsync(nodeb, 0, (size_t)NNODES*256*4, stream);
  scatter_k<<<E_EDGES, 256, 0, stream>>>(wb, Yb, senders, nodeb);
  tp2_k<<<E_EDGES*64/256, 256, 0, stream>>>(nodeb, Vb, senders, vareps, t_pm, t_ij,
                                            t_val, tp0b);
  launch_mgemm(F_SILU,        xb,   tp0b,   256, 320, Wt_l21, 256, bufB, envb, alpha, nullptr, stream);
  launch_mgemm(F_SILU,        bufB, nullptr,256, 256, Wt_l22, 256, bufA, envb, alpha, nullptr, stream);
  launch_mgemm(F_ENV|F_RESID, bufA, nullptr,256, 256, Wt_l23, 256, xb,   envb, alpha, xb,      stream);

  // ---- head ----
  launch_mgemm(F_NONE, xb, nullptr, 256, 256, Wt_h, 128, bufB, envb, alpha, nullptr, stream);
  final_k<<<E_EDGES/256, 256, 0, stream>>>(bufB, W_out, envb, (float*)d_out);
}